// Round 3
// baseline (644.755 us; speedup 1.0000x reference)
//
#include <hip/hip_runtime.h>

#define NN 50000
#define NE 800000
#define DIM 128
#define NG 64
#define ETOT (NE + NN)
#define NEG_SLOPE 0.2f
#define PB 200          // pooling blocks; chunk = 250 nodes
#define MAXLG 8         // local graph slots per block
#define NPW 10          // nodes per wave in persistent aggregation (50000/10 = 5000 waves)
#define STILE 4096      // src-tile: 4096 nodes * 512B = 2MB window (fits per-XCD L2)

// ============================ CSR build ============================

__global__ __launch_bounds__(256) void k_init(int* deg, int* fill, float* pooled, float* cnt) {
  int i = blockIdx.x * 256 + threadIdx.x;
  if (i < NN) { deg[i] = 1; fill[i] = 1; }          // 1 = self-loop
  if (i < NG * DIM) pooled[i] = 0.f;
  if (i < NG) cnt[i] = 0.f;
}

__global__ __launch_bounds__(256) void k_count(const int* __restrict__ dst, int* __restrict__ deg) {
  int e = blockIdx.x * 256 + threadIdx.x;
  if (e < NE) atomicAdd(&deg[dst[e]], 1);
}

// single-block inclusive scan -> offs[i+1] = sum(deg[0..i]), offs[0] = 0
__global__ __launch_bounds__(1024) void k_scan(const int* __restrict__ deg, int* __restrict__ offs) {
  __shared__ int wsum[16];
  __shared__ int carry_s;
  const int tid = threadIdx.x;
  const int lane = tid & 63, wid = tid >> 6;
  if (tid == 0) { carry_s = 0; offs[0] = 0; }
  __syncthreads();
  for (int base = 0; base < NN; base += 1024) {
    int i = base + tid;
    int x = (i < NN) ? deg[i] : 0;
#pragma unroll
    for (int off = 1; off < 64; off <<= 1) {
      int t = __shfl_up(x, off, 64);
      if (lane >= off) x += t;
    }
    if (lane == 63) wsum[wid] = x;
    __syncthreads();
    if (wid == 0) {
      int w = (lane < 16) ? wsum[lane] : 0;
#pragma unroll
      for (int off = 1; off < 16; off <<= 1) {
        int t = __shfl_up(w, off, 64);
        if (lane >= off) w += t;
      }
      if (lane < 16) wsum[lane] = w;
    }
    __syncthreads();
    int carry = carry_s;
    int wpre = (wid > 0) ? wsum[wid - 1] : 0;
    if (i < NN) offs[i + 1] = carry + wpre + x;
    __syncthreads();
    if (tid == 1023) carry_s = carry + wsum[15];
    __syncthreads();
  }
}

__global__ __launch_bounds__(256) void k_selfloop(const int* __restrict__ offs, int* __restrict__ csr) {
  int i = blockIdx.x * 256 + threadIdx.x;
  if (i < NN) csr[offs[i]] = i;   // slot 0 of each segment = self-loop
}

__global__ __launch_bounds__(256) void k_scatter(const int* __restrict__ src, const int* __restrict__ dst,
                                                 const int* __restrict__ offs, int* __restrict__ fill,
                                                 int* __restrict__ csr) {
  int e = blockIdx.x * 256 + threadIdx.x;
  if (e < NE) {
    int d = dst[e];
    int p = offs[d] + atomicAdd(&fill[d], 1);
    csr[p] = src[e];
  }
}

// sort each node's adjacency by src value: one wave per node, odd-even
// transposition over 64 lanes (deg <= 64 covers all nodes at E/N = 16).
// Order within a segment doesn't affect semantics (softmax + sum are
// order-invariant); this is purely a locality transform.
__global__ __launch_bounds__(256) void k_sortadj(const int* __restrict__ offs, int* __restrict__ csr) {
  int wave = (blockIdx.x * 256 + threadIdx.x) >> 6;
  int l = threadIdx.x & 63;
  if (wave >= NN) return;
  int beg = offs[wave], end = offs[wave + 1];
  int deg = end - beg;
  if (deg < 2 || deg > 64) return;            // deg>64 is ~1e-4 probability: skip (locality only)
  int val = (l < deg) ? csr[beg + l] : 0x7fffffff;
#pragma unroll
  for (int p = 0; p < 64; ++p) {
    int par;
    if ((p & 1) == 0) par = l ^ 1;
    else par = (l == 0 || l == 63) ? l : ((l & 1) ? l + 1 : l - 1);
    int oth = __shfl(val, par, 64);
    int mn = min(val, oth), mx = max(val, oth);
    val = (par == l) ? val : ((l < par) ? mn : mx);
  }
  if (l < deg) csr[beg + l] = val;
}

// ============================ GEMM h = X @ W  (X:[n,128], W:[128,128]) ============================

__global__ __launch_bounds__(256) void k_gemm(const float* __restrict__ X, const float* __restrict__ W,
                                              float* __restrict__ H, int n) {
  __shared__ float sA[64][36];
  __shared__ float sB[32][132];
  const int tid = threadIdx.x;
  const int tx = tid & 15;
  const int ty = tid >> 4;
  const int row0 = blockIdx.x * 64;
  float acc[4][8];
#pragma unroll
  for (int i = 0; i < 4; ++i)
#pragma unroll
    for (int j = 0; j < 8; ++j) acc[i][j] = 0.f;

  for (int k0 = 0; k0 < DIM; k0 += 32) {
#pragma unroll
    for (int i = 0; i < 2; ++i) {
      int idx = tid + i * 256;
      int r = idx >> 3, c4 = idx & 7;
      int rg = row0 + r; if (rg > n - 1) rg = n - 1;
      float4 v = *(const float4*)(X + (size_t)rg * DIM + k0 + c4 * 4);
      *(float4*)&sA[r][c4 * 4] = v;
    }
#pragma unroll
    for (int i = 0; i < 4; ++i) {
      int idx = tid + i * 256;
      int k = idx >> 5, c4 = idx & 31;
      float4 v = *(const float4*)(W + (size_t)(k0 + k) * DIM + c4 * 4);
      *(float4*)&sB[k][c4 * 4] = v;
    }
    __syncthreads();
#pragma unroll 8
    for (int k = 0; k < 32; ++k) {
      float a[4], b[8];
#pragma unroll
      for (int i = 0; i < 4; ++i) a[i] = sA[ty * 4 + i][k];
      float4 b0 = *(const float4*)&sB[k][tx * 8];
      float4 b1 = *(const float4*)&sB[k][tx * 8 + 4];
      b[0] = b0.x; b[1] = b0.y; b[2] = b0.z; b[3] = b0.w;
      b[4] = b1.x; b[5] = b1.y; b[6] = b1.z; b[7] = b1.w;
#pragma unroll
      for (int i = 0; i < 4; ++i)
#pragma unroll
        for (int j = 0; j < 8; ++j) acc[i][j] = fmaf(a[i], b[j], acc[i][j]);
    }
    __syncthreads();
  }
#pragma unroll
  for (int i = 0; i < 4; ++i) {
    int r = row0 + ty * 4 + i;
    if (r < n) {
      float4 v0 = make_float4(acc[i][0], acc[i][1], acc[i][2], acc[i][3]);
      float4 v1 = make_float4(acc[i][4], acc[i][5], acc[i][6], acc[i][7]);
      *(float4*)(H + (size_t)r * DIM + tx * 8) = v0;
      *(float4*)(H + (size_t)r * DIM + tx * 8 + 4) = v1;
    }
  }
}

// ============================ alpha_s/d[i] = h[i] . a_s / a_d ============================

__global__ __launch_bounds__(256) void k_alpha(const float* __restrict__ h, const float* __restrict__ a_s,
                                               const float* __restrict__ a_d, float* __restrict__ alpha_s,
                                               float* __restrict__ alpha_d) {
  int wave = (blockIdx.x * 256 + threadIdx.x) >> 6;
  int l = threadIdx.x & 63;
  if (wave >= NN) return;
  float2 hv = *(const float2*)(h + (size_t)wave * DIM + 2 * l);
  float2 vs = *(const float2*)(a_s + 2 * l);
  float2 vd = *(const float2*)(a_d + 2 * l);
  float ps = hv.x * vs.x + hv.y * vs.y;
  float pd = hv.x * vd.x + hv.y * vd.y;
#pragma unroll
  for (int off = 1; off < 64; off <<= 1) {
    ps += __shfl_xor(ps, off, 64);
    pd += __shfl_xor(pd, off, 64);
  }
  if (l == 0) { alpha_s[wave] = ps; alpha_d[wave] = pd; }
}

// ============================ edge softmax -> coef (CSR order) ============================

__global__ __launch_bounds__(256) void k_softmax(const int* __restrict__ offs, const int* __restrict__ csr,
                                                 const float* __restrict__ alpha_s, const float* __restrict__ alpha_d,
                                                 float* __restrict__ coef) {
  int tid = blockIdx.x * 256 + threadIdx.x;
  int node = tid >> 4;
  int l = tid & 15;
  if (node >= NN) return;
  int beg = offs[node], end = offs[node + 1];
  float ad = alpha_d[node];
  float m = -1e30f;
  for (int j = beg + l; j < end; j += 16) {
    float sc = alpha_s[csr[j]] + ad;
    sc = sc > 0.f ? sc : NEG_SLOPE * sc;
    m = fmaxf(m, sc);
  }
#pragma unroll
  for (int off = 1; off < 16; off <<= 1) m = fmaxf(m, __shfl_xor(m, off, 64));
  float ssum = 0.f;
  for (int j = beg + l; j < end; j += 16) {
    float sc = alpha_s[csr[j]] + ad;
    sc = sc > 0.f ? sc : NEG_SLOPE * sc;
    float ex = __expf(sc - m);
    coef[j] = ex;
    ssum += ex;
  }
#pragma unroll
  for (int off = 1; off < 16; off <<= 1) ssum += __shfl_xor(ssum, off, 64);
  float inv = 1.f / (ssum + 1e-16f);
  for (int j = beg + l; j < end; j += 16) coef[j] *= inv;
}

// ============================ persistent src-tiled aggregation ============================
// 5000 waves (all co-resident), NPW nodes each, cursors+accumulators in registers.
// Sweeps src in STILE-node windows so all waves gather from the same ~2MB
// window concurrently -> per-XCD L2 hits instead of fabric re-fetches.

__global__ __launch_bounds__(256) void k_aggr_p(const int* __restrict__ offs, const int* __restrict__ csr,
                                                const float* __restrict__ coef, const float* __restrict__ h,
                                                const float* __restrict__ bias, float* __restrict__ out) {
  const int wave = (blockIdx.x * 256 + threadIdx.x) >> 6;   // 0..4999
  const int l = threadIdx.x & 63;
  const int n0 = wave * NPW;
  int cur[NPW], endv[NPW];
  float2 acc[NPW];
#pragma unroll
  for (int i = 0; i < NPW; ++i) {
    cur[i] = offs[n0 + i];
    endv[i] = offs[n0 + i + 1];
    acc[i] = make_float2(0.f, 0.f);
  }
  for (int bound = STILE; ; bound += STILE) {
#pragma unroll
    for (int i = 0; i < NPW; ++i) {
      int c = cur[i], e = endv[i];
      float2 a = acc[i];
      while (c < e) {
        int s = csr[c];
        if (s >= bound) break;
        float cf = coef[c];
        float2 hv = *(const float2*)(h + (size_t)s * DIM + 2 * l);
        a.x = fmaf(cf, hv.x, a.x);
        a.y = fmaf(cf, hv.y, a.y);
        ++c;
      }
      cur[i] = c; acc[i] = a;
    }
    if (bound >= NN) break;
  }
  float2 b = *(const float2*)(bias + 2 * l);
#pragma unroll
  for (int i = 0; i < NPW; ++i) {
    float2 a = acc[i];
    a.x += b.x; a.y += b.y;
    *(float2*)(out + (size_t)(n0 + i) * DIM + 2 * l) = a;
  }
}

// ============================ global mean pool (hierarchical, batch sorted) ============================

__global__ __launch_bounds__(256) void k_pool_partial(const float* __restrict__ feats,
                                                      const int* __restrict__ batch,
                                                      float* __restrict__ pooled, float* __restrict__ cnt) {
  __shared__ float acc[4][MAXLG][DIM];
  __shared__ float lcnt[4][MAXLG];
  const int tid = threadIdx.x;
  const int wid = tid >> 6, l = tid & 63;
  for (int i = tid; i < 4 * MAXLG * DIM; i += 256) ((float*)acc)[i] = 0.f;
  if (tid < 4 * MAXLG) ((float*)lcnt)[tid] = 0.f;
  __syncthreads();

  const int chunk = (NN + PB - 1) / PB;
  const int beg = blockIdx.x * chunk;
  const int end = min(beg + chunk, NN);
  const int g0 = (beg < NN) ? batch[beg] : 0;

  for (int node = beg + wid; node < end; node += 4) {
    int lg = batch[node] - g0;
    float2 v = *(const float2*)(feats + (size_t)node * DIM + 2 * l);
    if (lg < MAXLG) {
      acc[wid][lg][2 * l] += v.x;
      acc[wid][lg][2 * l + 1] += v.y;
      if (l == 0) lcnt[wid][lg] += 1.f;
    } else {
      atomicAdd(&pooled[(g0 + lg) * DIM + 2 * l], v.x);
      atomicAdd(&pooled[(g0 + lg) * DIM + 2 * l + 1], v.y);
      if (l == 0) atomicAdd(&cnt[g0 + lg], 1.f);
    }
  }
  __syncthreads();

  for (int i = tid; i < MAXLG * DIM; i += 256) {
    int lg = i >> 7, d = i & (DIM - 1);
    float s = acc[0][lg][d] + acc[1][lg][d] + acc[2][lg][d] + acc[3][lg][d];
    if (s != 0.f) atomicAdd(&pooled[(g0 + lg) * DIM + d], s);
  }
  if (tid < MAXLG) {
    float s = lcnt[0][tid] + lcnt[1][tid] + lcnt[2][tid] + lcnt[3][tid];
    if (s != 0.f) atomicAdd(&cnt[g0 + tid], s);
  }
}

__global__ __launch_bounds__(256) void k_pool_norm(float* pooled, const float* __restrict__ cnt) {
  int i = blockIdx.x * 256 + threadIdx.x;
  if (i < NG * DIM) pooled[i] /= fmaxf(cnt[i >> 7], 1.f);
}

// ============================ launch ============================

static inline size_t pad256(size_t x) { return (x + 255) & ~(size_t)255; }

extern "C" void kernel_launch(void* const* d_in, const int* in_sizes, int n_in,
                              void* d_out, int out_size, void* d_ws, size_t ws_size,
                              hipStream_t stream) {
  const float* x   = (const float*)d_in[0];
  const int* ei    = (const int*)d_in[1];
  const int* batch = (const int*)d_in[2];
  const float* W1  = (const float*)d_in[3];
  const float* as1 = (const float*)d_in[4];
  const float* ad1 = (const float*)d_in[5];
  const float* b1  = (const float*)d_in[6];
  const float* W2  = (const float*)d_in[7];
  const float* as2 = (const float*)d_in[8];
  const float* ad2 = (const float*)d_in[9];
  const float* b2  = (const float*)d_in[10];

  float* out_feats = (float*)d_out;
  float* pooled    = out_feats + (size_t)NN * DIM;

  const int* src = ei;
  const int* dst = ei + NE;

  char* w = (char*)d_ws;
  float* h  = (float*)w;      w += pad256((size_t)NN * DIM * 4);
  float* f1 = (float*)w;      w += pad256((size_t)NN * DIM * 4);
  float* alpha_s = (float*)w; w += pad256((size_t)NN * 4);
  float* alpha_d = (float*)w; w += pad256((size_t)NN * 4);
  int* deg  = (int*)w;        w += pad256((size_t)NN * 4);
  int* offs = (int*)w;        w += pad256((size_t)(NN + 1) * 4);
  int* fill = (int*)w;        w += pad256((size_t)NN * 4);
  int* csr  = (int*)w;        w += pad256((size_t)ETOT * 4);
  float* coef = (float*)w;    w += pad256((size_t)ETOT * 4);
  float* cnt  = (float*)w;    w += pad256((size_t)NG * 4);

  const int NB_N = (NN + 255) / 256;
  const int NB_E = (NE + 255) / 256;
  const int NB_W = (NN * 64 + 255) / 256;
  const int NB_S = (NN * 16 + 255) / 256;
  const int NB_G = (NN + 63) / 64;
  const int NB_A = (NN / NPW) / 4;              // 1250 persistent blocks

  // CSR build (graph shared by both layers)
  k_init<<<NB_N, 256, 0, stream>>>(deg, fill, pooled, cnt);
  k_count<<<NB_E, 256, 0, stream>>>(dst, deg);
  k_scan<<<1, 1024, 0, stream>>>(deg, offs);
  k_selfloop<<<NB_N, 256, 0, stream>>>(offs, csr);
  k_scatter<<<NB_E, 256, 0, stream>>>(src, dst, offs, fill, csr);
  k_sortadj<<<NB_W, 256, 0, stream>>>(offs, csr);

  // layer 1
  k_gemm<<<NB_G, 256, 0, stream>>>(x, W1, h, NN);
  k_alpha<<<NB_W, 256, 0, stream>>>(h, as1, ad1, alpha_s, alpha_d);
  k_softmax<<<NB_S, 256, 0, stream>>>(offs, csr, alpha_s, alpha_d, coef);
  k_aggr_p<<<NB_A, 256, 0, stream>>>(offs, csr, coef, h, b1, f1);

  // layer 2
  k_gemm<<<NB_G, 256, 0, stream>>>(f1, W2, h, NN);
  k_alpha<<<NB_W, 256, 0, stream>>>(h, as2, ad2, alpha_s, alpha_d);
  k_softmax<<<NB_S, 256, 0, stream>>>(offs, csr, alpha_s, alpha_d, coef);
  k_aggr_p<<<NB_A, 256, 0, stream>>>(offs, csr, coef, h, b2, out_feats);

  // pool
  k_pool_partial<<<PB, 256, 0, stream>>>(out_feats, batch, pooled, cnt);
  k_pool_norm<<<(NG * DIM + 255) / 256, 256, 0, stream>>>(pooled, cnt);
}

// Round 4
// 343.914 us; speedup vs baseline: 1.8748x; 1.8748x over previous
//
#include <hip/hip_runtime.h>

#define NN 50000
#define NE 800000
#define DIM 128
#define NG 64
#define ETOT (NE + NN)
#define NEG_SLOPE 0.2f
#define PB 200          // pooling blocks; chunk = 250 nodes
#define MAXLG 8         // local graph slots per block

typedef unsigned int uint32;
typedef unsigned short ushort16;

static __device__ __forceinline__ uint32 f2bf_pack(float lo, float hi) {
  uint32 a = __float_as_uint(lo), b = __float_as_uint(hi);
  a = (a + 0x7fffu + ((a >> 16) & 1u)) >> 16;          // RNE
  b = (b + 0x7fffu + ((b >> 16) & 1u)) >> 16;
  return a | (b << 16);
}
static __device__ __forceinline__ float bf_lo(uint32 u) { return __uint_as_float(u << 16); }
static __device__ __forceinline__ float bf_hi(uint32 u) { return __uint_as_float(u & 0xffff0000u); }

// ============================ CSR build ============================

__global__ __launch_bounds__(256) void k_init(int* deg, int* fill, float* pooled, float* cnt) {
  int i = blockIdx.x * 256 + threadIdx.x;
  if (i < NN) { deg[i] = 1; fill[i] = 1; }          // 1 = self-loop
  if (i < NG * DIM) pooled[i] = 0.f;
  if (i < NG) cnt[i] = 0.f;
}

__global__ __launch_bounds__(256) void k_count(const int* __restrict__ dst, int* __restrict__ deg) {
  int e = blockIdx.x * 256 + threadIdx.x;
  if (e < NE) atomicAdd(&deg[dst[e]], 1);
}

// single-block inclusive scan -> offs[i+1] = sum(deg[0..i]), offs[0] = 0
__global__ __launch_bounds__(1024) void k_scan(const int* __restrict__ deg, int* __restrict__ offs) {
  __shared__ int wsum[16];
  __shared__ int carry_s;
  const int tid = threadIdx.x;
  const int lane = tid & 63, wid = tid >> 6;
  if (tid == 0) { carry_s = 0; offs[0] = 0; }
  __syncthreads();
  for (int base = 0; base < NN; base += 1024) {
    int i = base + tid;
    int x = (i < NN) ? deg[i] : 0;
#pragma unroll
    for (int off = 1; off < 64; off <<= 1) {
      int t = __shfl_up(x, off, 64);
      if (lane >= off) x += t;
    }
    if (lane == 63) wsum[wid] = x;
    __syncthreads();
    if (wid == 0) {
      int w = (lane < 16) ? wsum[lane] : 0;
#pragma unroll
      for (int off = 1; off < 16; off <<= 1) {
        int t = __shfl_up(w, off, 64);
        if (lane >= off) w += t;
      }
      if (lane < 16) wsum[lane] = w;
    }
    __syncthreads();
    int carry = carry_s;
    int wpre = (wid > 0) ? wsum[wid - 1] : 0;
    if (i < NN) offs[i + 1] = carry + wpre + x;
    __syncthreads();
    if (tid == 1023) carry_s = carry + wsum[15];
    __syncthreads();
  }
}

__global__ __launch_bounds__(256) void k_selfloop(const int* __restrict__ offs, int* __restrict__ csr) {
  int i = blockIdx.x * 256 + threadIdx.x;
  if (i < NN) csr[offs[i]] = i;   // slot 0 of each segment = self-loop
}

__global__ __launch_bounds__(256) void k_scatter(const int* __restrict__ src, const int* __restrict__ dst,
                                                 const int* __restrict__ offs, int* __restrict__ fill,
                                                 int* __restrict__ csr) {
  int e = blockIdx.x * 256 + threadIdx.x;
  if (e < NE) {
    int d = dst[e];
    int p = offs[d] + atomicAdd(&fill[d], 1);
    csr[p] = src[e];
  }
}

// ============== GEMM h = X @ W, h stored bf16-packed; alpha fused in epilogue ==============
// BM=64, BK=32, block 256, thread tile 4 rows x 8 cols. tid = ty*16+tx:
// for fixed ty the 16 threads tx=0..15 are consecutive lanes of one wave ->
// alpha row-reduction is a 16-lane shuffle tree.

__global__ __launch_bounds__(256) void k_gemm(const float* __restrict__ X, const float* __restrict__ W,
                                              const float* __restrict__ a_s, const float* __restrict__ a_d,
                                              uint32* __restrict__ H16,
                                              float* __restrict__ alpha_s, float* __restrict__ alpha_d,
                                              int n) {
  __shared__ float sA[64][36];
  __shared__ float sB[32][132];
  const int tid = threadIdx.x;
  const int tx = tid & 15;
  const int ty = tid >> 4;
  const int row0 = blockIdx.x * 64;
  float acc[4][8];
#pragma unroll
  for (int i = 0; i < 4; ++i)
#pragma unroll
    for (int j = 0; j < 8; ++j) acc[i][j] = 0.f;

  for (int k0 = 0; k0 < DIM; k0 += 32) {
#pragma unroll
    for (int i = 0; i < 2; ++i) {
      int idx = tid + i * 256;
      int r = idx >> 3, c4 = idx & 7;
      int rg = row0 + r; if (rg > n - 1) rg = n - 1;
      float4 v = *(const float4*)(X + (size_t)rg * DIM + k0 + c4 * 4);
      *(float4*)&sA[r][c4 * 4] = v;
    }
#pragma unroll
    for (int i = 0; i < 4; ++i) {
      int idx = tid + i * 256;
      int k = idx >> 5, c4 = idx & 31;
      float4 v = *(const float4*)(W + (size_t)(k0 + k) * DIM + c4 * 4);
      *(float4*)&sB[k][c4 * 4] = v;
    }
    __syncthreads();
#pragma unroll 8
    for (int k = 0; k < 32; ++k) {
      float a[4], b[8];
#pragma unroll
      for (int i = 0; i < 4; ++i) a[i] = sA[ty * 4 + i][k];
      float4 b0 = *(const float4*)&sB[k][tx * 8];
      float4 b1 = *(const float4*)&sB[k][tx * 8 + 4];
      b[0] = b0.x; b[1] = b0.y; b[2] = b0.z; b[3] = b0.w;
      b[4] = b1.x; b[5] = b1.y; b[6] = b1.z; b[7] = b1.w;
#pragma unroll
      for (int i = 0; i < 4; ++i)
#pragma unroll
        for (int j = 0; j < 8; ++j) acc[i][j] = fmaf(a[i], b[j], acc[i][j]);
    }
    __syncthreads();
  }

  // attention vectors for this thread's 8 columns
  float4 s0 = *(const float4*)(a_s + tx * 8);
  float4 s1 = *(const float4*)(a_s + tx * 8 + 4);
  float4 d0 = *(const float4*)(a_d + tx * 8);
  float4 d1 = *(const float4*)(a_d + tx * 8 + 4);

#pragma unroll
  for (int i = 0; i < 4; ++i) {
    int r = row0 + ty * 4 + i;
    if (r < n) {
      // bf16-packed row store: 8 bf16 = 4 uints = 16B
      uint32 p0 = f2bf_pack(acc[i][0], acc[i][1]);
      uint32 p1 = f2bf_pack(acc[i][2], acc[i][3]);
      uint32 p2 = f2bf_pack(acc[i][4], acc[i][5]);
      uint32 p3 = f2bf_pack(acc[i][6], acc[i][7]);
      uint4 pv = make_uint4(p0, p1, p2, p3);
      *(uint4*)(H16 + (size_t)r * 64 + tx * 4) = pv;
    }
    // fused alpha: partial dot over this thread's 8 cols, 16-lane reduce
    float ps = acc[i][0] * s0.x + acc[i][1] * s0.y + acc[i][2] * s0.z + acc[i][3] * s0.w
             + acc[i][4] * s1.x + acc[i][5] * s1.y + acc[i][6] * s1.z + acc[i][7] * s1.w;
    float pd = acc[i][0] * d0.x + acc[i][1] * d0.y + acc[i][2] * d0.z + acc[i][3] * d0.w
             + acc[i][4] * d1.x + acc[i][5] * d1.y + acc[i][6] * d1.z + acc[i][7] * d1.w;
#pragma unroll
    for (int off = 1; off < 16; off <<= 1) {
      ps += __shfl_xor(ps, off, 64);
      pd += __shfl_xor(pd, off, 64);
    }
    if (tx == 0 && r < n) { alpha_s[r] = ps; alpha_d[r] = pd; }
  }
}

// ============================ edge softmax -> coef (CSR order) ============================

__global__ __launch_bounds__(256) void k_softmax(const int* __restrict__ offs, const int* __restrict__ csr,
                                                 const float* __restrict__ alpha_s, const float* __restrict__ alpha_d,
                                                 float* __restrict__ coef) {
  int tid = blockIdx.x * 256 + threadIdx.x;
  int node = tid >> 4;
  int l = tid & 15;
  if (node >= NN) return;
  int beg = offs[node], end = offs[node + 1];
  float ad = alpha_d[node];
  float m = -1e30f;
  for (int j = beg + l; j < end; j += 16) {
    float sc = alpha_s[csr[j]] + ad;
    sc = sc > 0.f ? sc : NEG_SLOPE * sc;
    m = fmaxf(m, sc);
  }
#pragma unroll
  for (int off = 1; off < 16; off <<= 1) m = fmaxf(m, __shfl_xor(m, off, 64));
  float ssum = 0.f;
  for (int j = beg + l; j < end; j += 16) {
    float sc = alpha_s[csr[j]] + ad;
    sc = sc > 0.f ? sc : NEG_SLOPE * sc;
    float ex = __expf(sc - m);
    coef[j] = ex;
    ssum += ex;
  }
#pragma unroll
  for (int off = 1; off < 16; off <<= 1) ssum += __shfl_xor(ssum, off, 64);
  float inv = 1.f / (ssum + 1e-16f);
  for (int j = beg + l; j < end; j += 16) coef[j] *= inv;
}

// ============ aggregate: out[i] = sum_j coef[j]*h_bf16[src_j] + bias (f32 accum) ============
// one wave per node; lane l owns elements 2l,2l+1 (one packed uint per row);
// 4-way unroll for outstanding-load concurrency.

__global__ __launch_bounds__(256) void k_aggr(const int* __restrict__ offs, const int* __restrict__ csr,
                                              const float* __restrict__ coef, const uint32* __restrict__ H16,
                                              const float* __restrict__ bias, float* __restrict__ out) {
  int wave = (blockIdx.x * 256 + threadIdx.x) >> 6;
  int l = threadIdx.x & 63;
  if (wave >= NN) return;
  int beg = offs[wave], end = offs[wave + 1];
  float ax = 0.f, ay = 0.f;
  int j = beg;
  for (; j + 3 < end; j += 4) {
    int s0 = csr[j], s1 = csr[j + 1], s2 = csr[j + 2], s3 = csr[j + 3];
    float c0 = coef[j], c1 = coef[j + 1], c2 = coef[j + 2], c3 = coef[j + 3];
    uint32 u0 = H16[(size_t)s0 * 64 + l];
    uint32 u1 = H16[(size_t)s1 * 64 + l];
    uint32 u2 = H16[(size_t)s2 * 64 + l];
    uint32 u3 = H16[(size_t)s3 * 64 + l];
    ax = fmaf(c0, bf_lo(u0), ax); ay = fmaf(c0, bf_hi(u0), ay);
    ax = fmaf(c1, bf_lo(u1), ax); ay = fmaf(c1, bf_hi(u1), ay);
    ax = fmaf(c2, bf_lo(u2), ax); ay = fmaf(c2, bf_hi(u2), ay);
    ax = fmaf(c3, bf_lo(u3), ax); ay = fmaf(c3, bf_hi(u3), ay);
  }
  for (; j < end; ++j) {
    float c0 = coef[j];
    uint32 u0 = H16[(size_t)csr[j] * 64 + l];
    ax = fmaf(c0, bf_lo(u0), ax); ay = fmaf(c0, bf_hi(u0), ay);
  }
  float2 b = *(const float2*)(bias + 2 * l);
  float2 o = make_float2(ax + b.x, ay + b.y);
  *(float2*)(out + (size_t)wave * DIM + 2 * l) = o;
}

// ============================ global mean pool (hierarchical, batch sorted) ============================

__global__ __launch_bounds__(256) void k_pool_partial(const float* __restrict__ feats,
                                                      const int* __restrict__ batch,
                                                      float* __restrict__ pooled, float* __restrict__ cnt) {
  __shared__ float acc[4][MAXLG][DIM];
  __shared__ float lcnt[4][MAXLG];
  const int tid = threadIdx.x;
  const int wid = tid >> 6, l = tid & 63;
  for (int i = tid; i < 4 * MAXLG * DIM; i += 256) ((float*)acc)[i] = 0.f;
  if (tid < 4 * MAXLG) ((float*)lcnt)[tid] = 0.f;
  __syncthreads();

  const int chunk = (NN + PB - 1) / PB;
  const int beg = blockIdx.x * chunk;
  const int end = min(beg + chunk, NN);
  const int g0 = (beg < NN) ? batch[beg] : 0;

  for (int node = beg + wid; node < end; node += 4) {
    int lg = batch[node] - g0;
    float2 v = *(const float2*)(feats + (size_t)node * DIM + 2 * l);
    if (lg < MAXLG) {
      acc[wid][lg][2 * l] += v.x;
      acc[wid][lg][2 * l + 1] += v.y;
      if (l == 0) lcnt[wid][lg] += 1.f;
    } else {
      atomicAdd(&pooled[(g0 + lg) * DIM + 2 * l], v.x);
      atomicAdd(&pooled[(g0 + lg) * DIM + 2 * l + 1], v.y);
      if (l == 0) atomicAdd(&cnt[g0 + lg], 1.f);
    }
  }
  __syncthreads();

  for (int i = tid; i < MAXLG * DIM; i += 256) {
    int lg = i >> 7, d = i & (DIM - 1);
    float s = acc[0][lg][d] + acc[1][lg][d] + acc[2][lg][d] + acc[3][lg][d];
    if (s != 0.f) atomicAdd(&pooled[(g0 + lg) * DIM + d], s);
  }
  if (tid < MAXLG) {
    float s = lcnt[0][tid] + lcnt[1][tid] + lcnt[2][tid] + lcnt[3][tid];
    if (s != 0.f) atomicAdd(&cnt[g0 + tid], s);
  }
}

__global__ __launch_bounds__(256) void k_pool_norm(float* pooled, const float* __restrict__ cnt) {
  int i = blockIdx.x * 256 + threadIdx.x;
  if (i < NG * DIM) pooled[i] /= fmaxf(cnt[i >> 7], 1.f);
}

// ============================ launch ============================

static inline size_t pad256(size_t x) { return (x + 255) & ~(size_t)255; }

extern "C" void kernel_launch(void* const* d_in, const int* in_sizes, int n_in,
                              void* d_out, int out_size, void* d_ws, size_t ws_size,
                              hipStream_t stream) {
  const float* x   = (const float*)d_in[0];
  const int* ei    = (const int*)d_in[1];
  const int* batch = (const int*)d_in[2];
  const float* W1  = (const float*)d_in[3];
  const float* as1 = (const float*)d_in[4];
  const float* ad1 = (const float*)d_in[5];
  const float* b1  = (const float*)d_in[6];
  const float* W2  = (const float*)d_in[7];
  const float* as2 = (const float*)d_in[8];
  const float* ad2 = (const float*)d_in[9];
  const float* b2  = (const float*)d_in[10];

  float* out_feats = (float*)d_out;
  float* pooled    = out_feats + (size_t)NN * DIM;

  const int* src = ei;
  const int* dst = ei + NE;

  char* w = (char*)d_ws;
  uint32* h16 = (uint32*)w;   w += pad256((size_t)NN * 64 * 4);    // bf16-packed h (12.8 MB)
  float* f1 = (float*)w;      w += pad256((size_t)NN * DIM * 4);
  float* alpha_s = (float*)w; w += pad256((size_t)NN * 4);
  float* alpha_d = (float*)w; w += pad256((size_t)NN * 4);
  int* deg  = (int*)w;        w += pad256((size_t)NN * 4);
  int* offs = (int*)w;        w += pad256((size_t)(NN + 1) * 4);
  int* fill = (int*)w;        w += pad256((size_t)NN * 4);
  int* csr  = (int*)w;        w += pad256((size_t)ETOT * 4);
  float* coef = (float*)w;    w += pad256((size_t)ETOT * 4);
  float* cnt  = (float*)w;    w += pad256((size_t)NG * 4);

  const int NB_N = (NN + 255) / 256;
  const int NB_E = (NE + 255) / 256;
  const int NB_W = (NN * 64 + 255) / 256;
  const int NB_S = (NN * 16 + 255) / 256;
  const int NB_G = (NN + 63) / 64;

  // CSR build (graph shared by both layers)
  k_init<<<NB_N, 256, 0, stream>>>(deg, fill, pooled, cnt);
  k_count<<<NB_E, 256, 0, stream>>>(dst, deg);
  k_scan<<<1, 1024, 0, stream>>>(deg, offs);
  k_selfloop<<<NB_N, 256, 0, stream>>>(offs, csr);
  k_scatter<<<NB_E, 256, 0, stream>>>(src, dst, offs, fill, csr);

  // layer 1
  k_gemm<<<NB_G, 256, 0, stream>>>(x, W1, as1, ad1, h16, alpha_s, alpha_d, NN);
  k_softmax<<<NB_S, 256, 0, stream>>>(offs, csr, alpha_s, alpha_d, coef);
  k_aggr<<<NB_W, 256, 0, stream>>>(offs, csr, coef, h16, b1, f1);

  // layer 2
  k_gemm<<<NB_G, 256, 0, stream>>>(f1, W2, as2, ad2, h16, alpha_s, alpha_d, NN);
  k_softmax<<<NB_S, 256, 0, stream>>>(offs, csr, alpha_s, alpha_d, coef);
  k_aggr<<<NB_W, 256, 0, stream>>>(offs, csr, coef, h16, b2, out_feats);

  // pool
  k_pool_partial<<<PB, 256, 0, stream>>>(out_feats, batch, pooled, cnt);
  k_pool_norm<<<(NG * DIM + 255) / 256, 256, 0, stream>>>(pooled, cnt);
}

// Round 5
// 291.890 us; speedup vs baseline: 2.2089x; 1.1782x over previous
//
#include <hip/hip_runtime.h>

#define NN 50000
#define NE 800000
#define DIM 128
#define NG 64
#define ETOT (NE + NN)
#define NEG_SLOPE 0.2f
#define PB 200          // pooling blocks; chunk = 250 nodes
#define MAXLG 8         // local graph slots per block
#define NSH 8           // dst shards (== XCDs)
#define SHW ((NN + NSH - 1) / NSH)   // 6250 nodes per shard
#define NB_SCAN ((NN + 255) / 256)   // 196

typedef unsigned int uint32;

static __device__ __forceinline__ uint32 f2bf_pack(float lo, float hi) {
  uint32 a = __float_as_uint(lo), b = __float_as_uint(hi);
  a = (a + 0x7fffu + ((a >> 16) & 1u)) >> 16;          // RNE
  b = (b + 0x7fffu + ((b >> 16) & 1u)) >> 16;
  return a | (b << 16);
}
static __device__ __forceinline__ float bf_lo(uint32 u) { return __uint_as_float(u << 16); }
static __device__ __forceinline__ float bf_hi(uint32 u) { return __uint_as_float(u & 0xffff0000u); }

// ============================ CSR build ============================

__global__ __launch_bounds__(256) void k_init(int* deg, int* fill, float* pooled, float* cnt) {
  int i = blockIdx.x * 256 + threadIdx.x;
  if (i < NN) { deg[i] = 1; fill[i] = 1; }          // 1 = self-loop
  if (i < NG * DIM) pooled[i] = 0.f;
  if (i < NG) cnt[i] = 0.f;
}

__global__ __launch_bounds__(256) void k_count(const int* __restrict__ dst, int* __restrict__ deg) {
  int e = blockIdx.x * 256 + threadIdx.x;
  if (e < NE) atomicAdd(&deg[dst[e]], 1);
}

// ---- 3-phase multi-block inclusive scan: offs[i+1] = sum(deg[0..i]) ----

__global__ __launch_bounds__(256) void k_scan1(const int* __restrict__ deg, int* __restrict__ offs,
                                               int* __restrict__ bsum) {
  __shared__ int ws[4];
  const int i = blockIdx.x * 256 + threadIdx.x;
  const int lane = threadIdx.x & 63, wid = threadIdx.x >> 6;
  int x = (i < NN) ? deg[i] : 0;
#pragma unroll
  for (int off = 1; off < 64; off <<= 1) {
    int t = __shfl_up(x, off, 64);
    if (lane >= off) x += t;
  }
  if (lane == 63) ws[wid] = x;
  __syncthreads();
  int pre = 0;
#pragma unroll
  for (int j = 0; j < 3; ++j) if (j < wid) pre += ws[j];
  x += pre;
  if (i < NN) offs[i + 1] = x;
  if (threadIdx.x == 255) bsum[blockIdx.x] = x;
}

__global__ __launch_bounds__(256) void k_scan2(const int* __restrict__ bsum, int* __restrict__ bpre) {
  __shared__ int ws[4];
  const int b = threadIdx.x;
  const int lane = b & 63, wid = b >> 6;
  int v = (b < NB_SCAN) ? bsum[b] : 0;
  int x = v;
#pragma unroll
  for (int off = 1; off < 64; off <<= 1) {
    int t = __shfl_up(x, off, 64);
    if (lane >= off) x += t;
  }
  if (lane == 63) ws[wid] = x;
  __syncthreads();
  int pre = 0;
#pragma unroll
  for (int j = 0; j < 3; ++j) if (j < wid) pre += ws[j];
  x += pre;
  if (b < NB_SCAN) bpre[b] = x - v;     // exclusive prefix of block totals
}

__global__ __launch_bounds__(256) void k_scan3(int* __restrict__ offs, const int* __restrict__ bpre) {
  const int i = blockIdx.x * 256 + threadIdx.x;
  if (i < NN) offs[i + 1] += bpre[blockIdx.x];
  if (i == 0) offs[0] = 0;
}

__global__ __launch_bounds__(256) void k_selfloop(const int* __restrict__ offs, int* __restrict__ csr) {
  int i = blockIdx.x * 256 + threadIdx.x;
  if (i < NN) csr[offs[i]] = i;   // slot 0 of each segment = self-loop
}

// XCD-sharded scatter: blocks with blockIdx&7 == r own dst-shard r (blocks are
// dispatched round-robin over the 8 XCDs, so each csr line is dirtied by a
// single XCD's L2 -> full-line write-back instead of 16x amplification).
// Coverage is complete regardless of the actual block->XCD mapping.
__global__ __launch_bounds__(256) void k_scatter(const int* __restrict__ src, const int* __restrict__ dst,
                                                 const int* __restrict__ offs, int* __restrict__ fill,
                                                 int* __restrict__ csr) {
  const int r = blockIdx.x & (NSH - 1);
  const int bi = blockIdx.x >> 3;
  const int nb = gridDim.x >> 3;
  const int lo = r * SHW, hi = min(lo + SHW, NN);
  for (int e = bi * 256 + threadIdx.x; e < NE; e += nb * 256) {
    int d = dst[e];
    if (d >= lo && d < hi) {
      int p = offs[d] + atomicAdd(&fill[d], 1);
      csr[p] = src[e];
    }
  }
}

// ============== GEMM h = X @ W, h stored bf16-packed; alpha fused in epilogue ==============

__global__ __launch_bounds__(256) void k_gemm(const float* __restrict__ X, const float* __restrict__ W,
                                              const float* __restrict__ a_s, const float* __restrict__ a_d,
                                              uint32* __restrict__ H16,
                                              float* __restrict__ alpha_s, float* __restrict__ alpha_d,
                                              int n) {
  __shared__ float sA[64][36];
  __shared__ float sB[32][132];
  const int tid = threadIdx.x;
  const int tx = tid & 15;
  const int ty = tid >> 4;
  const int row0 = blockIdx.x * 64;
  float acc[4][8];
#pragma unroll
  for (int i = 0; i < 4; ++i)
#pragma unroll
    for (int j = 0; j < 8; ++j) acc[i][j] = 0.f;

  for (int k0 = 0; k0 < DIM; k0 += 32) {
#pragma unroll
    for (int i = 0; i < 2; ++i) {
      int idx = tid + i * 256;
      int r = idx >> 3, c4 = idx & 7;
      int rg = row0 + r; if (rg > n - 1) rg = n - 1;
      float4 v = *(const float4*)(X + (size_t)rg * DIM + k0 + c4 * 4);
      *(float4*)&sA[r][c4 * 4] = v;
    }
#pragma unroll
    for (int i = 0; i < 4; ++i) {
      int idx = tid + i * 256;
      int k = idx >> 5, c4 = idx & 31;
      float4 v = *(const float4*)(W + (size_t)(k0 + k) * DIM + c4 * 4);
      *(float4*)&sB[k][c4 * 4] = v;
    }
    __syncthreads();
#pragma unroll 8
    for (int k = 0; k < 32; ++k) {
      float a[4], b[8];
#pragma unroll
      for (int i = 0; i < 4; ++i) a[i] = sA[ty * 4 + i][k];
      float4 b0 = *(const float4*)&sB[k][tx * 8];
      float4 b1 = *(const float4*)&sB[k][tx * 8 + 4];
      b[0] = b0.x; b[1] = b0.y; b[2] = b0.z; b[3] = b0.w;
      b[4] = b1.x; b[5] = b1.y; b[6] = b1.z; b[7] = b1.w;
#pragma unroll
      for (int i = 0; i < 4; ++i)
#pragma unroll
        for (int j = 0; j < 8; ++j) acc[i][j] = fmaf(a[i], b[j], acc[i][j]);
    }
    __syncthreads();
  }

  float4 s0 = *(const float4*)(a_s + tx * 8);
  float4 s1 = *(const float4*)(a_s + tx * 8 + 4);
  float4 d0 = *(const float4*)(a_d + tx * 8);
  float4 d1 = *(const float4*)(a_d + tx * 8 + 4);

#pragma unroll
  for (int i = 0; i < 4; ++i) {
    int r = row0 + ty * 4 + i;
    if (r < n) {
      uint32 p0 = f2bf_pack(acc[i][0], acc[i][1]);
      uint32 p1 = f2bf_pack(acc[i][2], acc[i][3]);
      uint32 p2 = f2bf_pack(acc[i][4], acc[i][5]);
      uint32 p3 = f2bf_pack(acc[i][6], acc[i][7]);
      uint4 pv = make_uint4(p0, p1, p2, p3);
      *(uint4*)(H16 + (size_t)r * 64 + tx * 4) = pv;
    }
    float ps = acc[i][0] * s0.x + acc[i][1] * s0.y + acc[i][2] * s0.z + acc[i][3] * s0.w
             + acc[i][4] * s1.x + acc[i][5] * s1.y + acc[i][6] * s1.z + acc[i][7] * s1.w;
    float pd = acc[i][0] * d0.x + acc[i][1] * d0.y + acc[i][2] * d0.z + acc[i][3] * d0.w
             + acc[i][4] * d1.x + acc[i][5] * d1.y + acc[i][6] * d1.z + acc[i][7] * d1.w;
#pragma unroll
    for (int off = 1; off < 16; off <<= 1) {
      ps += __shfl_xor(ps, off, 64);
      pd += __shfl_xor(pd, off, 64);
    }
    if (tx == 0 && r < n) { alpha_s[r] = ps; alpha_d[r] = pd; }
  }
}

// ============================ edge softmax -> coef (CSR order) ============================

__global__ __launch_bounds__(256) void k_softmax(const int* __restrict__ offs, const int* __restrict__ csr,
                                                 const float* __restrict__ alpha_s, const float* __restrict__ alpha_d,
                                                 float* __restrict__ coef) {
  int tid = blockIdx.x * 256 + threadIdx.x;
  int node = tid >> 4;
  int l = tid & 15;
  if (node >= NN) return;
  int beg = offs[node], end = offs[node + 1];
  float ad = alpha_d[node];
  float m = -1e30f;
  for (int j = beg + l; j < end; j += 16) {
    float sc = alpha_s[csr[j]] + ad;
    sc = sc > 0.f ? sc : NEG_SLOPE * sc;
    m = fmaxf(m, sc);
  }
#pragma unroll
  for (int off = 1; off < 16; off <<= 1) m = fmaxf(m, __shfl_xor(m, off, 64));
  float ssum = 0.f;
  for (int j = beg + l; j < end; j += 16) {
    float sc = alpha_s[csr[j]] + ad;
    sc = sc > 0.f ? sc : NEG_SLOPE * sc;
    float ex = __expf(sc - m);
    coef[j] = ex;
    ssum += ex;
  }
#pragma unroll
  for (int off = 1; off < 16; off <<= 1) ssum += __shfl_xor(ssum, off, 64);
  float inv = 1.f / (ssum + 1e-16f);
  for (int j = beg + l; j < end; j += 16) coef[j] *= inv;
}

// ============ aggregate: out[i] = sum_j coef[j]*h_bf16[src_j] + bias (f32 accum) ============

__global__ __launch_bounds__(256) void k_aggr(const int* __restrict__ offs, const int* __restrict__ csr,
                                              const float* __restrict__ coef, const uint32* __restrict__ H16,
                                              const float* __restrict__ bias, float* __restrict__ out) {
  int wave = (blockIdx.x * 256 + threadIdx.x) >> 6;
  int l = threadIdx.x & 63;
  if (wave >= NN) return;
  int beg = offs[wave], end = offs[wave + 1];
  float ax = 0.f, ay = 0.f;
  int j = beg;
  for (; j + 3 < end; j += 4) {
    int s0 = csr[j], s1 = csr[j + 1], s2 = csr[j + 2], s3 = csr[j + 3];
    float c0 = coef[j], c1 = coef[j + 1], c2 = coef[j + 2], c3 = coef[j + 3];
    uint32 u0 = H16[(size_t)s0 * 64 + l];
    uint32 u1 = H16[(size_t)s1 * 64 + l];
    uint32 u2 = H16[(size_t)s2 * 64 + l];
    uint32 u3 = H16[(size_t)s3 * 64 + l];
    ax = fmaf(c0, bf_lo(u0), ax); ay = fmaf(c0, bf_hi(u0), ay);
    ax = fmaf(c1, bf_lo(u1), ax); ay = fmaf(c1, bf_hi(u1), ay);
    ax = fmaf(c2, bf_lo(u2), ax); ay = fmaf(c2, bf_hi(u2), ay);
    ax = fmaf(c3, bf_lo(u3), ax); ay = fmaf(c3, bf_hi(u3), ay);
  }
  for (; j < end; ++j) {
    float c0 = coef[j];
    uint32 u0 = H16[(size_t)csr[j] * 64 + l];
    ax = fmaf(c0, bf_lo(u0), ax); ay = fmaf(c0, bf_hi(u0), ay);
  }
  float2 b = *(const float2*)(bias + 2 * l);
  float2 o = make_float2(ax + b.x, ay + b.y);
  *(float2*)(out + (size_t)wave * DIM + 2 * l) = o;
}

// ============================ global mean pool (hierarchical, batch sorted) ============================

__global__ __launch_bounds__(256) void k_pool_partial(const float* __restrict__ feats,
                                                      const int* __restrict__ batch,
                                                      float* __restrict__ pooled, float* __restrict__ cnt) {
  __shared__ float acc[4][MAXLG][DIM];
  __shared__ float lcnt[4][MAXLG];
  const int tid = threadIdx.x;
  const int wid = tid >> 6, l = tid & 63;
  for (int i = tid; i < 4 * MAXLG * DIM; i += 256) ((float*)acc)[i] = 0.f;
  if (tid < 4 * MAXLG) ((float*)lcnt)[tid] = 0.f;
  __syncthreads();

  const int chunk = (NN + PB - 1) / PB;
  const int beg = blockIdx.x * chunk;
  const int end = min(beg + chunk, NN);
  const int g0 = (beg < NN) ? batch[beg] : 0;

  for (int node = beg + wid; node < end; node += 4) {
    int lg = batch[node] - g0;
    float2 v = *(const float2*)(feats + (size_t)node * DIM + 2 * l);
    if (lg < MAXLG) {
      acc[wid][lg][2 * l] += v.x;
      acc[wid][lg][2 * l + 1] += v.y;
      if (l == 0) lcnt[wid][lg] += 1.f;
    } else {
      atomicAdd(&pooled[(g0 + lg) * DIM + 2 * l], v.x);
      atomicAdd(&pooled[(g0 + lg) * DIM + 2 * l + 1], v.y);
      if (l == 0) atomicAdd(&cnt[g0 + lg], 1.f);
    }
  }
  __syncthreads();

  for (int i = tid; i < MAXLG * DIM; i += 256) {
    int lg = i >> 7, d = i & (DIM - 1);
    float s = acc[0][lg][d] + acc[1][lg][d] + acc[2][lg][d] + acc[3][lg][d];
    if (s != 0.f) atomicAdd(&pooled[(g0 + lg) * DIM + d], s);
  }
  if (tid < MAXLG) {
    float s = lcnt[0][tid] + lcnt[1][tid] + lcnt[2][tid] + lcnt[3][tid];
    if (s != 0.f) atomicAdd(&cnt[g0 + tid], s);
  }
}

__global__ __launch_bounds__(256) void k_pool_norm(float* pooled, const float* __restrict__ cnt) {
  int i = blockIdx.x * 256 + threadIdx.x;
  if (i < NG * DIM) pooled[i] /= fmaxf(cnt[i >> 7], 1.f);
}

// ============================ launch ============================

static inline size_t pad256(size_t x) { return (x + 255) & ~(size_t)255; }

extern "C" void kernel_launch(void* const* d_in, const int* in_sizes, int n_in,
                              void* d_out, int out_size, void* d_ws, size_t ws_size,
                              hipStream_t stream) {
  const float* x   = (const float*)d_in[0];
  const int* ei    = (const int*)d_in[1];
  const int* batch = (const int*)d_in[2];
  const float* W1  = (const float*)d_in[3];
  const float* as1 = (const float*)d_in[4];
  const float* ad1 = (const float*)d_in[5];
  const float* b1  = (const float*)d_in[6];
  const float* W2  = (const float*)d_in[7];
  const float* as2 = (const float*)d_in[8];
  const float* ad2 = (const float*)d_in[9];
  const float* b2  = (const float*)d_in[10];

  float* out_feats = (float*)d_out;
  float* pooled    = out_feats + (size_t)NN * DIM;

  const int* src = ei;
  const int* dst = ei + NE;

  char* w = (char*)d_ws;
  uint32* h16 = (uint32*)w;   w += pad256((size_t)NN * 64 * 4);    // bf16-packed h (12.8 MB)
  float* f1 = (float*)w;      w += pad256((size_t)NN * DIM * 4);
  float* alpha_s = (float*)w; w += pad256((size_t)NN * 4);
  float* alpha_d = (float*)w; w += pad256((size_t)NN * 4);
  int* deg  = (int*)w;        w += pad256((size_t)NN * 4);
  int* offs = (int*)w;        w += pad256((size_t)(NN + 1) * 4);
  int* fill = (int*)w;        w += pad256((size_t)NN * 4);
  int* csr  = (int*)w;        w += pad256((size_t)ETOT * 4);
  float* coef = (float*)w;    w += pad256((size_t)ETOT * 4);
  float* cnt  = (float*)w;    w += pad256((size_t)NG * 4);
  int* bsum = (int*)w;        w += pad256((size_t)NB_SCAN * 4);
  int* bpre = (int*)w;        w += pad256((size_t)NB_SCAN * 4);

  const int NB_N = (NN + 255) / 256;
  const int NB_E = (NE + 255) / 256;
  const int NB_W = (NN * 64 + 255) / 256;
  const int NB_S = (NN * 16 + 255) / 256;
  const int NB_G = (NN + 63) / 64;
  const int NB_SC = 1024;                       // sharded scatter: 128 blocks x 8 shards

  // CSR build (graph shared by both layers)
  k_init<<<NB_N, 256, 0, stream>>>(deg, fill, pooled, cnt);
  k_count<<<NB_E, 256, 0, stream>>>(dst, deg);
  k_scan1<<<NB_SCAN, 256, 0, stream>>>(deg, offs, bsum);
  k_scan2<<<1, 256, 0, stream>>>(bsum, bpre);
  k_scan3<<<NB_SCAN, 256, 0, stream>>>(offs, bpre);
  k_selfloop<<<NB_N, 256, 0, stream>>>(offs, csr);
  k_scatter<<<NB_SC, 256, 0, stream>>>(src, dst, offs, fill, csr);

  // layer 1
  k_gemm<<<NB_G, 256, 0, stream>>>(x, W1, as1, ad1, h16, alpha_s, alpha_d, NN);
  k_softmax<<<NB_S, 256, 0, stream>>>(offs, csr, alpha_s, alpha_d, coef);
  k_aggr<<<NB_W, 256, 0, stream>>>(offs, csr, coef, h16, b1, f1);

  // layer 2
  k_gemm<<<NB_G, 256, 0, stream>>>(f1, W2, as2, ad2, h16, alpha_s, alpha_d, NN);
  k_softmax<<<NB_S, 256, 0, stream>>>(offs, csr, alpha_s, alpha_d, coef);
  k_aggr<<<NB_W, 256, 0, stream>>>(offs, csr, coef, h16, b2, out_feats);

  // pool
  k_pool_partial<<<PB, 256, 0, stream>>>(out_feats, batch, pooled, cnt);
  k_pool_norm<<<(NG * DIM + 255) / 256, 256, 0, stream>>>(pooled, cnt);
}

// Round 6
// 261.433 us; speedup vs baseline: 2.4662x; 1.1165x over previous
//
#include <hip/hip_runtime.h>

#define NN 50000
#define NE 800000
#define DIM 128
#define NG 64
#define ETOT (NE + NN)
#define NEG_SLOPE 0.2f
#define PB 200          // pooling blocks; chunk = 250 nodes
#define MAXLG 8         // local graph slots per block
#define NSH 8           // dst shards (== XCDs)
#define SHW ((NN + NSH - 1) / NSH)   // 6250 nodes per shard
#define NB_SCAN ((NN + 255) / 256)   // 196

typedef unsigned int uint32;

static __device__ __forceinline__ uint32 f2bf_pack(float lo, float hi) {
  uint32 a = __float_as_uint(lo), b = __float_as_uint(hi);
  a = (a + 0x7fffu + ((a >> 16) & 1u)) >> 16;          // RNE
  b = (b + 0x7fffu + ((b >> 16) & 1u)) >> 16;
  return a | (b << 16);
}
static __device__ __forceinline__ float bf_lo(uint32 u) { return __uint_as_float(u << 16); }
static __device__ __forceinline__ float bf_hi(uint32 u) { return __uint_as_float(u & 0xffff0000u); }

// ============================ CSR build ============================

__global__ __launch_bounds__(256) void k_init(int* deg, int* fill, float* pooled, float* cnt) {
  int i = blockIdx.x * 256 + threadIdx.x;
  if (i < NN) { deg[i] = 1; fill[i] = 1; }          // 1 = self-loop
  if (i < NG * DIM) pooled[i] = 0.f;
  if (i < NG) cnt[i] = 0.f;
}

__global__ __launch_bounds__(256) void k_count(const int* __restrict__ dst, int* __restrict__ deg) {
  int e = blockIdx.x * 256 + threadIdx.x;
  if (e < NE) atomicAdd(&deg[dst[e]], 1);
}

// ---- 3-phase multi-block inclusive scan: offs[i+1] = sum(deg[0..i]) ----

__global__ __launch_bounds__(256) void k_scan1(const int* __restrict__ deg, int* __restrict__ offs,
                                               int* __restrict__ bsum) {
  __shared__ int ws[4];
  const int i = blockIdx.x * 256 + threadIdx.x;
  const int lane = threadIdx.x & 63, wid = threadIdx.x >> 6;
  int x = (i < NN) ? deg[i] : 0;
#pragma unroll
  for (int off = 1; off < 64; off <<= 1) {
    int t = __shfl_up(x, off, 64);
    if (lane >= off) x += t;
  }
  if (lane == 63) ws[wid] = x;
  __syncthreads();
  int pre = 0;
#pragma unroll
  for (int j = 0; j < 3; ++j) if (j < wid) pre += ws[j];
  x += pre;
  if (i < NN) offs[i + 1] = x;
  if (threadIdx.x == 255) bsum[blockIdx.x] = x;
}

__global__ __launch_bounds__(256) void k_scan2(const int* __restrict__ bsum, int* __restrict__ bpre) {
  __shared__ int ws[4];
  const int b = threadIdx.x;
  const int lane = b & 63, wid = b >> 6;
  int v = (b < NB_SCAN) ? bsum[b] : 0;
  int x = v;
#pragma unroll
  for (int off = 1; off < 64; off <<= 1) {
    int t = __shfl_up(x, off, 64);
    if (lane >= off) x += t;
  }
  if (lane == 63) ws[wid] = x;
  __syncthreads();
  int pre = 0;
#pragma unroll
  for (int j = 0; j < 3; ++j) if (j < wid) pre += ws[j];
  x += pre;
  if (b < NB_SCAN) bpre[b] = x - v;     // exclusive prefix of block totals
}

__global__ __launch_bounds__(256) void k_scan3(int* __restrict__ offs, const int* __restrict__ bpre) {
  const int i = blockIdx.x * 256 + threadIdx.x;
  if (i < NN) offs[i + 1] += bpre[blockIdx.x];
  if (i == 0) offs[0] = 0;
}

__global__ __launch_bounds__(256) void k_selfloop(const int* __restrict__ offs, int* __restrict__ csr) {
  int i = blockIdx.x * 256 + threadIdx.x;
  if (i < NN) csr[offs[i]] = i;   // slot 0 of each segment = self-loop
}

// XCD-sharded scatter (see round-5 notes): each csr line dirtied by one XCD only.
__global__ __launch_bounds__(256) void k_scatter(const int* __restrict__ src, const int* __restrict__ dst,
                                                 const int* __restrict__ offs, int* __restrict__ fill,
                                                 int* __restrict__ csr) {
  const int r = blockIdx.x & (NSH - 1);
  const int bi = blockIdx.x >> 3;
  const int nb = gridDim.x >> 3;
  const int lo = r * SHW, hi = min(lo + SHW, NN);
  for (int e = bi * 256 + threadIdx.x; e < NE; e += nb * 256) {
    int d = dst[e];
    if (d >= lo && d < hi) {
      int p = offs[d] + atomicAdd(&fill[d], 1);
      csr[p] = src[e];
    }
  }
}

// ============== GEMM h = X @ W (f32 X), h stored bf16-packed; alpha fused in epilogue ==============

__global__ __launch_bounds__(256) void k_gemm(const float* __restrict__ X, const float* __restrict__ W,
                                              const float* __restrict__ a_s, const float* __restrict__ a_d,
                                              uint32* __restrict__ H16,
                                              float* __restrict__ alpha_s, float* __restrict__ alpha_d,
                                              int n) {
  __shared__ float sA[64][36];
  __shared__ float sB[32][132];
  const int tid = threadIdx.x;
  const int tx = tid & 15;
  const int ty = tid >> 4;
  const int row0 = blockIdx.x * 64;
  float acc[4][8];
#pragma unroll
  for (int i = 0; i < 4; ++i)
#pragma unroll
    for (int j = 0; j < 8; ++j) acc[i][j] = 0.f;

  for (int k0 = 0; k0 < DIM; k0 += 32) {
#pragma unroll
    for (int i = 0; i < 2; ++i) {
      int idx = tid + i * 256;
      int r = idx >> 3, c4 = idx & 7;
      int rg = row0 + r; if (rg > n - 1) rg = n - 1;
      float4 v = *(const float4*)(X + (size_t)rg * DIM + k0 + c4 * 4);
      *(float4*)&sA[r][c4 * 4] = v;
    }
#pragma unroll
    for (int i = 0; i < 4; ++i) {
      int idx = tid + i * 256;
      int k = idx >> 5, c4 = idx & 31;
      float4 v = *(const float4*)(W + (size_t)(k0 + k) * DIM + c4 * 4);
      *(float4*)&sB[k][c4 * 4] = v;
    }
    __syncthreads();
#pragma unroll 8
    for (int k = 0; k < 32; ++k) {
      float a[4], b[8];
#pragma unroll
      for (int i = 0; i < 4; ++i) a[i] = sA[ty * 4 + i][k];
      float4 b0 = *(const float4*)&sB[k][tx * 8];
      float4 b1 = *(const float4*)&sB[k][tx * 8 + 4];
      b[0] = b0.x; b[1] = b0.y; b[2] = b0.z; b[3] = b0.w;
      b[4] = b1.x; b[5] = b1.y; b[6] = b1.z; b[7] = b1.w;
#pragma unroll
      for (int i = 0; i < 4; ++i)
#pragma unroll
        for (int j = 0; j < 8; ++j) acc[i][j] = fmaf(a[i], b[j], acc[i][j]);
    }
    __syncthreads();
  }

  float4 s0 = *(const float4*)(a_s + tx * 8);
  float4 s1 = *(const float4*)(a_s + tx * 8 + 4);
  float4 d0 = *(const float4*)(a_d + tx * 8);
  float4 d1 = *(const float4*)(a_d + tx * 8 + 4);

#pragma unroll
  for (int i = 0; i < 4; ++i) {
    int r = row0 + ty * 4 + i;
    if (r < n) {
      uint4 pv = make_uint4(f2bf_pack(acc[i][0], acc[i][1]), f2bf_pack(acc[i][2], acc[i][3]),
                            f2bf_pack(acc[i][4], acc[i][5]), f2bf_pack(acc[i][6], acc[i][7]));
      *(uint4*)(H16 + (size_t)r * 64 + tx * 4) = pv;
    }
    float ps = acc[i][0] * s0.x + acc[i][1] * s0.y + acc[i][2] * s0.z + acc[i][3] * s0.w
             + acc[i][4] * s1.x + acc[i][5] * s1.y + acc[i][6] * s1.z + acc[i][7] * s1.w;
    float pd = acc[i][0] * d0.x + acc[i][1] * d0.y + acc[i][2] * d0.z + acc[i][3] * d0.w
             + acc[i][4] * d1.x + acc[i][5] * d1.y + acc[i][6] * d1.z + acc[i][7] * d1.w;
#pragma unroll
    for (int off = 1; off < 16; off <<= 1) {
      ps += __shfl_xor(ps, off, 64);
      pd += __shfl_xor(pd, off, 64);
    }
    if (tx == 0 && r < n) { alpha_s[r] = ps; alpha_d[r] = pd; }
  }
}

// ============== GEMM variant: X given as bf16-packed uints (layer 2) ==============

__global__ __launch_bounds__(256) void k_gemm16(const uint32* __restrict__ X16, const float* __restrict__ W,
                                                const float* __restrict__ a_s, const float* __restrict__ a_d,
                                                uint32* __restrict__ H16,
                                                float* __restrict__ alpha_s, float* __restrict__ alpha_d,
                                                int n) {
  __shared__ float sA[64][36];
  __shared__ float sB[32][132];
  const int tid = threadIdx.x;
  const int tx = tid & 15;
  const int ty = tid >> 4;
  const int row0 = blockIdx.x * 64;
  float acc[4][8];
#pragma unroll
  for (int i = 0; i < 4; ++i)
#pragma unroll
    for (int j = 0; j < 8; ++j) acc[i][j] = 0.f;

  for (int k0 = 0; k0 < DIM; k0 += 32) {
    {  // A tile: 64 rows x 16 uints (32 bf16); one uint4 per thread
      int r = tid >> 2, c = tid & 3;
      int rg = row0 + r; if (rg > n - 1) rg = n - 1;
      uint4 v = *(const uint4*)(X16 + (size_t)rg * 64 + (k0 >> 1) + c * 4);
      float* dst = &sA[r][c * 8];
      dst[0] = bf_lo(v.x); dst[1] = bf_hi(v.x);
      dst[2] = bf_lo(v.y); dst[3] = bf_hi(v.y);
      dst[4] = bf_lo(v.z); dst[5] = bf_hi(v.z);
      dst[6] = bf_lo(v.w); dst[7] = bf_hi(v.w);
    }
#pragma unroll
    for (int i = 0; i < 4; ++i) {
      int idx = tid + i * 256;
      int k = idx >> 5, c4 = idx & 31;
      float4 v = *(const float4*)(W + (size_t)(k0 + k) * DIM + c4 * 4);
      *(float4*)&sB[k][c4 * 4] = v;
    }
    __syncthreads();
#pragma unroll 8
    for (int k = 0; k < 32; ++k) {
      float a[4], b[8];
#pragma unroll
      for (int i = 0; i < 4; ++i) a[i] = sA[ty * 4 + i][k];
      float4 b0 = *(const float4*)&sB[k][tx * 8];
      float4 b1 = *(const float4*)&sB[k][tx * 8 + 4];
      b[0] = b0.x; b[1] = b0.y; b[2] = b0.z; b[3] = b0.w;
      b[4] = b1.x; b[5] = b1.y; b[6] = b1.z; b[7] = b1.w;
#pragma unroll
      for (int i = 0; i < 4; ++i)
#pragma unroll
        for (int j = 0; j < 8; ++j) acc[i][j] = fmaf(a[i], b[j], acc[i][j]);
    }
    __syncthreads();
  }

  float4 s0 = *(const float4*)(a_s + tx * 8);
  float4 s1 = *(const float4*)(a_s + tx * 8 + 4);
  float4 d0 = *(const float4*)(a_d + tx * 8);
  float4 d1 = *(const float4*)(a_d + tx * 8 + 4);

#pragma unroll
  for (int i = 0; i < 4; ++i) {
    int r = row0 + ty * 4 + i;
    if (r < n) {
      uint4 pv = make_uint4(f2bf_pack(acc[i][0], acc[i][1]), f2bf_pack(acc[i][2], acc[i][3]),
                            f2bf_pack(acc[i][4], acc[i][5]), f2bf_pack(acc[i][6], acc[i][7]));
      *(uint4*)(H16 + (size_t)r * 64 + tx * 4) = pv;
    }
    float ps = acc[i][0] * s0.x + acc[i][1] * s0.y + acc[i][2] * s0.z + acc[i][3] * s0.w
             + acc[i][4] * s1.x + acc[i][5] * s1.y + acc[i][6] * s1.z + acc[i][7] * s1.w;
    float pd = acc[i][0] * d0.x + acc[i][1] * d0.y + acc[i][2] * d0.z + acc[i][3] * d0.w
             + acc[i][4] * d1.x + acc[i][5] * d1.y + acc[i][6] * d1.z + acc[i][7] * d1.w;
#pragma unroll
    for (int off = 1; off < 16; off <<= 1) {
      ps += __shfl_xor(ps, off, 64);
      pd += __shfl_xor(pd, off, 64);
    }
    if (tx == 0 && r < n) { alpha_s[r] = ps; alpha_d[r] = pd; }
  }
}

// ============ fused edge-softmax + aggregation, one wave per node ============
// out[i] = (sum_j exp(sc_j - m) * h_src_j) / (sum_j exp(sc_j - m)) + bias
// Scores one-per-lane; (src, ex) broadcast to the wave via shfl during the
// feature-gather loop; normalization deferred to the epilogue (no coef array).

#define AGGR4(J)                                                        \
  { int s0 = __shfl(sv, (J), 64), s1 = __shfl(sv, (J) + 1, 64),         \
        s2 = __shfl(sv, (J) + 2, 64), s3 = __shfl(sv, (J) + 3, 64);     \
    float c0 = __shfl(ex, (J), 64), c1 = __shfl(ex, (J) + 1, 64),       \
          c2 = __shfl(ex, (J) + 2, 64), c3 = __shfl(ex, (J) + 3, 64);   \
    uint32 u0 = H16[(size_t)s0 * 64 + l];                               \
    uint32 u1 = H16[(size_t)s1 * 64 + l];                               \
    uint32 u2 = H16[(size_t)s2 * 64 + l];                               \
    uint32 u3 = H16[(size_t)s3 * 64 + l];                               \
    ax = fmaf(c0, bf_lo(u0), ax); ay = fmaf(c0, bf_hi(u0), ay);         \
    ax = fmaf(c1, bf_lo(u1), ax); ay = fmaf(c1, bf_hi(u1), ay);         \
    ax = fmaf(c2, bf_lo(u2), ax); ay = fmaf(c2, bf_hi(u2), ay);         \
    ax = fmaf(c3, bf_lo(u3), ax); ay = fmaf(c3, bf_hi(u3), ay); }

#define AGGR1(J)                                                        \
  { int s0 = __shfl(sv, (J), 64); float c0 = __shfl(ex, (J), 64);       \
    uint32 u0 = H16[(size_t)s0 * 64 + l];                               \
    ax = fmaf(c0, bf_lo(u0), ax); ay = fmaf(c0, bf_hi(u0), ay); }

template <int STORE16>
__global__ __launch_bounds__(256) void k_sm_aggr(const int* __restrict__ offs, const int* __restrict__ csr,
                                                 const float* __restrict__ alpha_s, const float* __restrict__ alpha_d,
                                                 const uint32* __restrict__ H16, const float* __restrict__ bias,
                                                 float* __restrict__ out, uint32* __restrict__ out16) {
  const int wave = (blockIdx.x * 256 + threadIdx.x) >> 6;
  const int l = threadIdx.x & 63;
  if (wave >= NN) return;
  const int beg = offs[wave], end = offs[wave + 1];
  const int deg = end - beg;
  const float ad = alpha_d[wave];
  float ax = 0.f, ay = 0.f, ssum = 0.f;

  if (deg <= 64) {                       // fast path: one chunk, csr read once
    int sv = 0; float sc = -1e30f;
    if (l < deg) {
      sv = csr[beg + l];
      sc = alpha_s[sv] + ad;
      sc = sc > 0.f ? sc : NEG_SLOPE * sc;
    }
    float m = sc;
#pragma unroll
    for (int off = 1; off < 64; off <<= 1) m = fmaxf(m, __shfl_xor(m, off, 64));
    float ex = (l < deg) ? __expf(sc - m) : 0.f;
    ssum = ex;
    int j = 0;
    for (; j + 3 < deg; j += 4) AGGR4(j);
    for (; j < deg; ++j) AGGR1(j);
  } else {                               // general path: chunked two-pass
    float m = -1e30f;
    for (int b = beg + l; b < end; b += 64) {
      float sc = alpha_s[csr[b]] + ad;
      sc = sc > 0.f ? sc : NEG_SLOPE * sc;
      m = fmaxf(m, sc);
    }
#pragma unroll
    for (int off = 1; off < 64; off <<= 1) m = fmaxf(m, __shfl_xor(m, off, 64));
    for (int base = beg; base < end; base += 64) {
      int nch = min(64, end - base);
      int sv = 0; float ex = 0.f;
      if (l < nch) {
        sv = csr[base + l];
        float sc = alpha_s[sv] + ad;
        sc = sc > 0.f ? sc : NEG_SLOPE * sc;
        ex = __expf(sc - m);
      }
      ssum += ex;
      int j = 0;
      for (; j + 3 < nch; j += 4) AGGR4(j);
      for (; j < nch; ++j) AGGR1(j);
    }
  }

#pragma unroll
  for (int off = 1; off < 64; off <<= 1) ssum += __shfl_xor(ssum, off, 64);
  const float inv = 1.f / (ssum + 1e-16f);
  float2 b = *(const float2*)(bias + 2 * l);
  float ox = ax * inv + b.x, oy = ay * inv + b.y;
  if (STORE16) {
    out16[(size_t)wave * 64 + l] = f2bf_pack(ox, oy);
  } else {
    *(float2*)(out + (size_t)wave * DIM + 2 * l) = make_float2(ox, oy);
  }
}

// ============================ global mean pool (hierarchical, batch sorted) ============================

__global__ __launch_bounds__(256) void k_pool_partial(const float* __restrict__ feats,
                                                      const int* __restrict__ batch,
                                                      float* __restrict__ pooled, float* __restrict__ cnt) {
  __shared__ float acc[4][MAXLG][DIM];
  __shared__ float lcnt[4][MAXLG];
  const int tid = threadIdx.x;
  const int wid = tid >> 6, l = tid & 63;
  for (int i = tid; i < 4 * MAXLG * DIM; i += 256) ((float*)acc)[i] = 0.f;
  if (tid < 4 * MAXLG) ((float*)lcnt)[tid] = 0.f;
  __syncthreads();

  const int chunk = (NN + PB - 1) / PB;
  const int beg = blockIdx.x * chunk;
  const int end = min(beg + chunk, NN);
  const int g0 = (beg < NN) ? batch[beg] : 0;

  for (int node = beg + wid; node < end; node += 4) {
    int lg = batch[node] - g0;
    float2 v = *(const float2*)(feats + (size_t)node * DIM + 2 * l);
    if (lg < MAXLG) {
      acc[wid][lg][2 * l] += v.x;
      acc[wid][lg][2 * l + 1] += v.y;
      if (l == 0) lcnt[wid][lg] += 1.f;
    } else {
      atomicAdd(&pooled[(g0 + lg) * DIM + 2 * l], v.x);
      atomicAdd(&pooled[(g0 + lg) * DIM + 2 * l + 1], v.y);
      if (l == 0) atomicAdd(&cnt[g0 + lg], 1.f);
    }
  }
  __syncthreads();

  for (int i = tid; i < MAXLG * DIM; i += 256) {
    int lg = i >> 7, d = i & (DIM - 1);
    float s = acc[0][lg][d] + acc[1][lg][d] + acc[2][lg][d] + acc[3][lg][d];
    if (s != 0.f) atomicAdd(&pooled[(g0 + lg) * DIM + d], s);
  }
  if (tid < MAXLG) {
    float s = lcnt[0][tid] + lcnt[1][tid] + lcnt[2][tid] + lcnt[3][tid];
    if (s != 0.f) atomicAdd(&cnt[g0 + tid], s);
  }
}

__global__ __launch_bounds__(256) void k_pool_norm(float* pooled, const float* __restrict__ cnt) {
  int i = blockIdx.x * 256 + threadIdx.x;
  if (i < NG * DIM) pooled[i] /= fmaxf(cnt[i >> 7], 1.f);
}

// ============================ launch ============================

static inline size_t pad256(size_t x) { return (x + 255) & ~(size_t)255; }

extern "C" void kernel_launch(void* const* d_in, const int* in_sizes, int n_in,
                              void* d_out, int out_size, void* d_ws, size_t ws_size,
                              hipStream_t stream) {
  const float* x   = (const float*)d_in[0];
  const int* ei    = (const int*)d_in[1];
  const int* batch = (const int*)d_in[2];
  const float* W1  = (const float*)d_in[3];
  const float* as1 = (const float*)d_in[4];
  const float* ad1 = (const float*)d_in[5];
  const float* b1  = (const float*)d_in[6];
  const float* W2  = (const float*)d_in[7];
  const float* as2 = (const float*)d_in[8];
  const float* ad2 = (const float*)d_in[9];
  const float* b2  = (const float*)d_in[10];

  float* out_feats = (float*)d_out;
  float* pooled    = out_feats + (size_t)NN * DIM;

  const int* src = ei;
  const int* dst = ei + NE;

  char* w = (char*)d_ws;
  uint32* h16 = (uint32*)w;   w += pad256((size_t)NN * 64 * 4);    // bf16-packed h (12.8 MB)
  uint32* f116 = (uint32*)w;  w += pad256((size_t)NN * 64 * 4);    // bf16-packed layer-1 out
  float* alpha_s = (float*)w; w += pad256((size_t)NN * 4);
  float* alpha_d = (float*)w; w += pad256((size_t)NN * 4);
  int* deg  = (int*)w;        w += pad256((size_t)NN * 4);
  int* offs = (int*)w;        w += pad256((size_t)(NN + 1) * 4);
  int* fill = (int*)w;        w += pad256((size_t)NN * 4);
  int* csr  = (int*)w;        w += pad256((size_t)ETOT * 4);
  float* cnt  = (float*)w;    w += pad256((size_t)NG * 4);
  int* bsum = (int*)w;        w += pad256((size_t)NB_SCAN * 4);
  int* bpre = (int*)w;        w += pad256((size_t)NB_SCAN * 4);

  const int NB_N = (NN + 255) / 256;
  const int NB_E = (NE + 255) / 256;
  const int NB_W = (NN * 64 + 255) / 256;
  const int NB_G = (NN + 63) / 64;
  const int NB_SC = 1024;                       // sharded scatter: 128 blocks x 8 shards

  // CSR build (graph shared by both layers)
  k_init<<<NB_N, 256, 0, stream>>>(deg, fill, pooled, cnt);
  k_count<<<NB_E, 256, 0, stream>>>(dst, deg);
  k_scan1<<<NB_SCAN, 256, 0, stream>>>(deg, offs, bsum);
  k_scan2<<<1, 256, 0, stream>>>(bsum, bpre);
  k_scan3<<<NB_SCAN, 256, 0, stream>>>(offs, bpre);
  k_selfloop<<<NB_N, 256, 0, stream>>>(offs, csr);
  k_scatter<<<NB_SC, 256, 0, stream>>>(src, dst, offs, fill, csr);

  // layer 1
  k_gemm<<<NB_G, 256, 0, stream>>>(x, W1, as1, ad1, h16, alpha_s, alpha_d, NN);
  k_sm_aggr<1><<<NB_W, 256, 0, stream>>>(offs, csr, alpha_s, alpha_d, h16, b1, nullptr, f116);

  // layer 2
  k_gemm16<<<NB_G, 256, 0, stream>>>(f116, W2, as2, ad2, h16, alpha_s, alpha_d, NN);
  k_sm_aggr<0><<<NB_W, 256, 0, stream>>>(offs, csr, alpha_s, alpha_d, h16, b2, out_feats, nullptr);

  // pool
  k_pool_partial<<<PB, 256, 0, stream>>>(out_feats, batch, pooled, cnt);
  k_pool_norm<<<(NG * DIM + 255) / 256, 256, 0, stream>>>(pooled, cnt);
}

// Round 7
// 222.947 us; speedup vs baseline: 2.8920x; 1.1726x over previous
//
#include <hip/hip_runtime.h>

#define NN 50000
#define NE 800000
#define DIM 128
#define NG 64
#define ETOT (NE + NN)
#define NEG_SLOPE 0.2f
#define PB 200          // pooling blocks; chunk = 250 nodes
#define MAXLG 8         // local graph slots per block
#define NSH 8           // dst shards (== XCDs)
#define SHW ((NN + NSH - 1) / NSH)   // 6250 nodes per shard
#define NB_SCAN ((NN + 255) / 256)   // 196

typedef unsigned int uint32;
typedef unsigned short ushort;
typedef short bf16x8 __attribute__((ext_vector_type(8)));
typedef float f32x4 __attribute__((ext_vector_type(4)));

static __device__ __forceinline__ uint32 f2bf_pack(float lo, float hi) {
  uint32 a = __float_as_uint(lo), b = __float_as_uint(hi);
  a = (a + 0x7fffu + ((a >> 16) & 1u)) >> 16;          // RNE
  b = (b + 0x7fffu + ((b >> 16) & 1u)) >> 16;
  return a | (b << 16);
}
static __device__ __forceinline__ ushort f2bf1(float x) {
  uint32 a = __float_as_uint(x);
  a = (a + 0x7fffu + ((a >> 16) & 1u)) >> 16;
  return (ushort)a;
}
static __device__ __forceinline__ float bf_lo(uint32 u) { return __uint_as_float(u << 16); }
static __device__ __forceinline__ float bf_hi(uint32 u) { return __uint_as_float(u & 0xffff0000u); }

// ============================ CSR build ============================

__global__ __launch_bounds__(256) void k_init(int* deg, int* fill, float* pooled, float* cnt) {
  int i = blockIdx.x * 256 + threadIdx.x;
  if (i < NN) { deg[i] = 1; fill[i] = 1; }          // 1 = self-loop
  if (i < NG * DIM) pooled[i] = 0.f;
  if (i < NG) cnt[i] = 0.f;
}

// one-time: W^T in bf16 (rows = output col n, contiguous k) for MFMA B-frags
__global__ __launch_bounds__(256) void k_prep(const float* __restrict__ W1, const float* __restrict__ W2,
                                              ushort* __restrict__ wt1, ushort* __restrict__ wt2) {
  int i = blockIdx.x * 256 + threadIdx.x;    // i = n*128 + k
  if (i < DIM * DIM) {
    int n = i >> 7, k = i & 127;
    wt1[i] = f2bf1(W1[k * DIM + n]);
    wt2[i] = f2bf1(W2[k * DIM + n]);
  }
}

__global__ __launch_bounds__(256) void k_count(const int* __restrict__ dst, int* __restrict__ deg) {
  int e = blockIdx.x * 256 + threadIdx.x;
  if (e < NE) atomicAdd(&deg[dst[e]], 1);
}

// ---- 3-phase multi-block inclusive scan: offs[i+1] = sum(deg[0..i]) ----

__global__ __launch_bounds__(256) void k_scan1(const int* __restrict__ deg, int* __restrict__ offs,
                                               int* __restrict__ bsum) {
  __shared__ int ws[4];
  const int i = blockIdx.x * 256 + threadIdx.x;
  const int lane = threadIdx.x & 63, wid = threadIdx.x >> 6;
  int x = (i < NN) ? deg[i] : 0;
#pragma unroll
  for (int off = 1; off < 64; off <<= 1) {
    int t = __shfl_up(x, off, 64);
    if (lane >= off) x += t;
  }
  if (lane == 63) ws[wid] = x;
  __syncthreads();
  int pre = 0;
#pragma unroll
  for (int j = 0; j < 3; ++j) if (j < wid) pre += ws[j];
  x += pre;
  if (i < NN) offs[i + 1] = x;
  if (threadIdx.x == 255) bsum[blockIdx.x] = x;
}

__global__ __launch_bounds__(256) void k_scan2(const int* __restrict__ bsum, int* __restrict__ bpre) {
  __shared__ int ws[4];
  const int b = threadIdx.x;
  const int lane = b & 63, wid = b >> 6;
  int v = (b < NB_SCAN) ? bsum[b] : 0;
  int x = v;
#pragma unroll
  for (int off = 1; off < 64; off <<= 1) {
    int t = __shfl_up(x, off, 64);
    if (lane >= off) x += t;
  }
  if (lane == 63) ws[wid] = x;
  __syncthreads();
  int pre = 0;
#pragma unroll
  for (int j = 0; j < 3; ++j) if (j < wid) pre += ws[j];
  x += pre;
  if (b < NB_SCAN) bpre[b] = x - v;     // exclusive prefix of block totals
}

__global__ __launch_bounds__(256) void k_scan3(int* __restrict__ offs, const int* __restrict__ bpre) {
  const int i = blockIdx.x * 256 + threadIdx.x;
  if (i < NN) offs[i + 1] += bpre[blockIdx.x];
  if (i == 0) offs[0] = 0;
}

__global__ __launch_bounds__(256) void k_selfloop(const int* __restrict__ offs, int* __restrict__ csr) {
  int i = blockIdx.x * 256 + threadIdx.x;
  if (i < NN) csr[offs[i]] = i;   // slot 0 of each segment = self-loop
}

// XCD-sharded scatter (round-5 notes): each csr line dirtied by one XCD only.
__global__ __launch_bounds__(256) void k_scatter(const int* __restrict__ src, const int* __restrict__ dst,
                                                 const int* __restrict__ offs, int* __restrict__ fill,
                                                 int* __restrict__ csr) {
  const int r = blockIdx.x & (NSH - 1);
  const int bi = blockIdx.x >> 3;
  const int nb = gridDim.x >> 3;
  const int lo = r * SHW, hi = min(lo + SHW, NN);
  for (int e = bi * 256 + threadIdx.x; e < NE; e += nb * 256) {
    int d = dst[e];
    if (d >= lo && d < hi) {
      int p = offs[d] + atomicAdd(&fill[d], 1);
      csr[p] = src[e];
    }
  }
}

// ============== MFMA GEMM: H16 = bf16(X @ W), alpha fused; A16=1 -> X is bf16-packed ==============
// 64 rows/block, 4 waves x 16 rows, K=128 staged once. XOR-swizzle byte^((row&7)<<4)
// keeps ds_read_b128 frag reads ~conflict-free (rows are 256B = bank-aligned otherwise).

template <int A16>
__global__ __launch_bounds__(256) void k_mm(const void* __restrict__ Xv, const ushort* __restrict__ WT,
                                            const float* __restrict__ a_s, const float* __restrict__ a_d,
                                            uint32* __restrict__ H16,
                                            float* __restrict__ alpha_s, float* __restrict__ alpha_d, int n) {
  __shared__ __align__(16) ushort sWT[DIM * DIM];   // 32 KB
  __shared__ __align__(16) ushort sA[64 * DIM];     // 16 KB
  const int tid = threadIdx.x;
  const int row0 = blockIdx.x * 64;

  {  // stage W^T -> LDS (swizzled); thread t covers 128B of row t>>1
    const int nr = tid >> 1, h2 = tid & 1;
    const uint4* wp = (const uint4*)(WT + nr * DIM + h2 * 64);
#pragma unroll
    for (int i = 0; i < 8; ++i) {
      uint4 v = wp[i];
      int byte = nr * 256 + (((h2 * 128 + i * 16)) ^ ((nr & 7) << 4));
      *(uint4*)((char*)sWT + byte) = v;
    }
  }
  {  // stage A -> LDS (bf16, swizzled); thread t: row t>>2, quarter t&3
    const int r = tid >> 2, q = tid & 3;
    int rg = row0 + r; if (rg > n - 1) rg = n - 1;
    if (A16) {
      const uint4* xp = (const uint4*)((const uint32*)Xv + (size_t)rg * 64 + q * 16);
#pragma unroll
      for (int i = 0; i < 4; ++i) {
        uint4 pk = xp[i];
        int byte = r * 256 + ((q * 64 + i * 16) ^ ((r & 7) << 4));
        *(uint4*)((char*)sA + byte) = pk;
      }
    } else {
      const float4* xp = (const float4*)((const float*)Xv + (size_t)rg * DIM + q * 32);
#pragma unroll
      for (int i = 0; i < 4; ++i) {
        float4 v0 = xp[2 * i], v1 = xp[2 * i + 1];
        uint4 pk = make_uint4(f2bf_pack(v0.x, v0.y), f2bf_pack(v0.z, v0.w),
                              f2bf_pack(v1.x, v1.y), f2bf_pack(v1.z, v1.w));
        int byte = r * 256 + ((q * 64 + i * 16) ^ ((r & 7) << 4));
        *(uint4*)((char*)sA + byte) = pk;
      }
    }
  }
  __syncthreads();

  const int l = tid & 63, wv = tid >> 6;
  const int jr = l & 15, g = l >> 4;       // col-in-tile / k-slice group
  const int m0 = wv * 16;                  // wave's row base within block
  f32x4 acc[8];
#pragma unroll
  for (int nt = 0; nt < 8; ++nt) acc[nt] = (f32x4){0.f, 0.f, 0.f, 0.f};

  const int ra = m0 + jr;
  const int abase = ra * 256, aswz = (ra & 7) << 4;
  const int bswz = (jr & 7) << 4;
#pragma unroll
  for (int kk = 0; kk < 4; ++kk) {
    const int kb = kk * 64 + g * 16;
    bf16x8 af = *(const bf16x8*)((const char*)sA + abase + (kb ^ aswz));
#pragma unroll
    for (int nt = 0; nt < 8; ++nt) {
      bf16x8 bfg = *(const bf16x8*)((const char*)sWT + (nt * 16 + jr) * 256 + (kb ^ bswz));
      acc[nt] = __builtin_amdgcn_mfma_f32_16x16x32_bf16(af, bfg, acc[nt], 0, 0, 0);
    }
  }

  // fused alpha from f32 accumulators: row = m0 + g*4 + j, col = nt*16 + jr
  float asv[8], adv[8];
#pragma unroll
  for (int nt = 0; nt < 8; ++nt) { asv[nt] = a_s[nt * 16 + jr]; adv[nt] = a_d[nt * 16 + jr]; }
#pragma unroll
  for (int j = 0; j < 4; ++j) {
    float ps = 0.f, pd = 0.f;
#pragma unroll
    for (int nt = 0; nt < 8; ++nt) {
      ps = fmaf(acc[nt][j], asv[nt], ps);
      pd = fmaf(acc[nt][j], adv[nt], pd);
    }
#pragma unroll
    for (int off = 1; off < 16; off <<= 1) {
      ps += __shfl_xor(ps, off, 64);
      pd += __shfl_xor(pd, off, 64);
    }
    int r = row0 + m0 + g * 4 + j;
    if (jr == 0 && r < n) { alpha_s[r] = ps; alpha_d[r] = pd; }
  }

  // bf16 output bounce through this wave's own sA rows (no barrier needed), then coalesced stores
  ushort* sOut = sA;
#pragma unroll
  for (int nt = 0; nt < 8; ++nt)
#pragma unroll
    for (int j = 0; j < 4; ++j)
      sOut[(m0 + g * 4 + j) * DIM + nt * 16 + jr] = f2bf1(acc[nt][j]);
#pragma unroll
  for (int i = 0; i < 4; ++i) {
    int r = row0 + m0 + (l >> 4) + i * 4;
    uint4 v = *(const uint4*)((const char*)sOut + m0 * 256 + l * 16 + i * 1024);
    if (r < n) *(uint4*)(H16 + (size_t)(row0 + m0) * 64 + l * 4 + i * 256) = v;
  }
}

// ============ fused edge-softmax + aggregation, one wave per node ============

#define AGGR4(J)                                                        \
  { int s0 = __shfl(sv, (J), 64), s1 = __shfl(sv, (J) + 1, 64),         \
        s2 = __shfl(sv, (J) + 2, 64), s3 = __shfl(sv, (J) + 3, 64);     \
    float c0 = __shfl(ex, (J), 64), c1 = __shfl(ex, (J) + 1, 64),       \
          c2 = __shfl(ex, (J) + 2, 64), c3 = __shfl(ex, (J) + 3, 64);   \
    uint32 u0 = H16[(size_t)s0 * 64 + l];                               \
    uint32 u1 = H16[(size_t)s1 * 64 + l];                               \
    uint32 u2 = H16[(size_t)s2 * 64 + l];                               \
    uint32 u3 = H16[(size_t)s3 * 64 + l];                               \
    ax = fmaf(c0, bf_lo(u0), ax); ay = fmaf(c0, bf_hi(u0), ay);         \
    ax = fmaf(c1, bf_lo(u1), ax); ay = fmaf(c1, bf_hi(u1), ay);         \
    ax = fmaf(c2, bf_lo(u2), ax); ay = fmaf(c2, bf_hi(u2), ay);         \
    ax = fmaf(c3, bf_lo(u3), ax); ay = fmaf(c3, bf_hi(u3), ay); }

#define AGGR1(J)                                                        \
  { int s0 = __shfl(sv, (J), 64); float c0 = __shfl(ex, (J), 64);       \
    uint32 u0 = H16[(size_t)s0 * 64 + l];                               \
    ax = fmaf(c0, bf_lo(u0), ax); ay = fmaf(c0, bf_hi(u0), ay); }

template <int STORE16>
__global__ __launch_bounds__(256) void k_sm_aggr(const int* __restrict__ offs, const int* __restrict__ csr,
                                                 const float* __restrict__ alpha_s, const float* __restrict__ alpha_d,
                                                 const uint32* __restrict__ H16, const float* __restrict__ bias,
                                                 float* __restrict__ out, uint32* __restrict__ out16) {
  const int wave = (blockIdx.x * 256 + threadIdx.x) >> 6;
  const int l = threadIdx.x & 63;
  if (wave >= NN) return;
  const int beg = offs[wave], end = offs[wave + 1];
  const int deg = end - beg;
  const float ad = alpha_d[wave];
  float ax = 0.f, ay = 0.f, ssum = 0.f;

  if (deg <= 64) {                       // fast path
    int sv = 0; float sc = -1e30f;
    if (l < deg) {
      sv = csr[beg + l];
      sc = alpha_s[sv] + ad;
      sc = sc > 0.f ? sc : NEG_SLOPE * sc;
    }
    float m = sc;
#pragma unroll
    for (int off = 1; off < 64; off <<= 1) m = fmaxf(m, __shfl_xor(m, off, 64));
    float ex = (l < deg) ? __expf(sc - m) : 0.f;
    ssum = ex;
    int j = 0;
    for (; j + 3 < deg; j += 4) AGGR4(j);
    for (; j < deg; ++j) AGGR1(j);
  } else {                               // chunked two-pass
    float m = -1e30f;
    for (int b = beg + l; b < end; b += 64) {
      float sc = alpha_s[csr[b]] + ad;
      sc = sc > 0.f ? sc : NEG_SLOPE * sc;
      m = fmaxf(m, sc);
    }
#pragma unroll
    for (int off = 1; off < 64; off <<= 1) m = fmaxf(m, __shfl_xor(m, off, 64));
    for (int base = beg; base < end; base += 64) {
      int nch = min(64, end - base);
      int sv = 0; float ex = 0.f;
      if (l < nch) {
        sv = csr[base + l];
        float sc = alpha_s[sv] + ad;
        sc = sc > 0.f ? sc : NEG_SLOPE * sc;
        ex = __expf(sc - m);
      }
      ssum += ex;
      int j = 0;
      for (; j + 3 < nch; j += 4) AGGR4(j);
      for (; j < nch; ++j) AGGR1(j);
    }
  }

#pragma unroll
  for (int off = 1; off < 64; off <<= 1) ssum += __shfl_xor(ssum, off, 64);
  const float inv = 1.f / (ssum + 1e-16f);
  float2 b = *(const float2*)(bias + 2 * l);
  float ox = ax * inv + b.x, oy = ay * inv + b.y;
  if (STORE16) {
    out16[(size_t)wave * 64 + l] = f2bf_pack(ox, oy);
  } else {
    *(float2*)(out + (size_t)wave * DIM + 2 * l) = make_float2(ox, oy);
  }
}

// ============================ global mean pool (hierarchical, batch sorted) ============================

__global__ __launch_bounds__(256) void k_pool_partial(const float* __restrict__ feats,
                                                      const int* __restrict__ batch,
                                                      float* __restrict__ pooled, float* __restrict__ cnt) {
  __shared__ float acc[4][MAXLG][DIM];
  __shared__ float lcnt[4][MAXLG];
  const int tid = threadIdx.x;
  const int wid = tid >> 6, l = tid & 63;
  for (int i = tid; i < 4 * MAXLG * DIM; i += 256) ((float*)acc)[i] = 0.f;
  if (tid < 4 * MAXLG) ((float*)lcnt)[tid] = 0.f;
  __syncthreads();

  const int chunk = (NN + PB - 1) / PB;
  const int beg = blockIdx.x * chunk;
  const int end = min(beg + chunk, NN);
  const int g0 = (beg < NN) ? batch[beg] : 0;

  for (int node = beg + wid; node < end; node += 4) {
    int lg = batch[node] - g0;
    float2 v = *(const float2*)(feats + (size_t)node * DIM + 2 * l);
    if (lg < MAXLG) {
      acc[wid][lg][2 * l] += v.x;
      acc[wid][lg][2 * l + 1] += v.y;
      if (l == 0) lcnt[wid][lg] += 1.f;
    } else {
      atomicAdd(&pooled[(g0 + lg) * DIM + 2 * l], v.x);
      atomicAdd(&pooled[(g0 + lg) * DIM + 2 * l + 1], v.y);
      if (l == 0) atomicAdd(&cnt[g0 + lg], 1.f);
    }
  }
  __syncthreads();

  for (int i = tid; i < MAXLG * DIM; i += 256) {
    int lg = i >> 7, d = i & (DIM - 1);
    float s = acc[0][lg][d] + acc[1][lg][d] + acc[2][lg][d] + acc[3][lg][d];
    if (s != 0.f) atomicAdd(&pooled[(g0 + lg) * DIM + d], s);
  }
  if (tid < MAXLG) {
    float s = lcnt[0][tid] + lcnt[1][tid] + lcnt[2][tid] + lcnt[3][tid];
    if (s != 0.f) atomicAdd(&cnt[g0 + tid], s);
  }
}

__global__ __launch_bounds__(256) void k_pool_norm(float* pooled, const float* __restrict__ cnt) {
  int i = blockIdx.x * 256 + threadIdx.x;
  if (i < NG * DIM) pooled[i] /= fmaxf(cnt[i >> 7], 1.f);
}

// ============================ launch ============================

static inline size_t pad256(size_t x) { return (x + 255) & ~(size_t)255; }

extern "C" void kernel_launch(void* const* d_in, const int* in_sizes, int n_in,
                              void* d_out, int out_size, void* d_ws, size_t ws_size,
                              hipStream_t stream) {
  const float* x   = (const float*)d_in[0];
  const int* ei    = (const int*)d_in[1];
  const int* batch = (const int*)d_in[2];
  const float* W1  = (const float*)d_in[3];
  const float* as1 = (const float*)d_in[4];
  const float* ad1 = (const float*)d_in[5];
  const float* b1  = (const float*)d_in[6];
  const float* W2  = (const float*)d_in[7];
  const float* as2 = (const float*)d_in[8];
  const float* ad2 = (const float*)d_in[9];
  const float* b2  = (const float*)d_in[10];

  float* out_feats = (float*)d_out;
  float* pooled    = out_feats + (size_t)NN * DIM;

  const int* src = ei;
  const int* dst = ei + NE;

  char* w = (char*)d_ws;
  uint32* h16 = (uint32*)w;   w += pad256((size_t)NN * 64 * 4);    // bf16-packed h (12.8 MB)
  uint32* f116 = (uint32*)w;  w += pad256((size_t)NN * 64 * 4);    // bf16-packed layer-1 out
  float* alpha_s = (float*)w; w += pad256((size_t)NN * 4);
  float* alpha_d = (float*)w; w += pad256((size_t)NN * 4);
  int* deg  = (int*)w;        w += pad256((size_t)NN * 4);
  int* offs = (int*)w;        w += pad256((size_t)(NN + 1) * 4);
  int* fill = (int*)w;        w += pad256((size_t)NN * 4);
  int* csr  = (int*)w;        w += pad256((size_t)ETOT * 4);
  float* cnt  = (float*)w;    w += pad256((size_t)NG * 4);
  int* bsum = (int*)w;        w += pad256((size_t)NB_SCAN * 4);
  int* bpre = (int*)w;        w += pad256((size_t)NB_SCAN * 4);
  ushort* wt1 = (ushort*)w;   w += pad256((size_t)DIM * DIM * 2);
  ushort* wt2 = (ushort*)w;   w += pad256((size_t)DIM * DIM * 2);

  const int NB_N = (NN + 255) / 256;
  const int NB_E = (NE + 255) / 256;
  const int NB_W = (NN * 64 + 255) / 256;
  const int NB_G = (NN + 63) / 64;
  const int NB_SC = 1024;                       // sharded scatter: 128 blocks x 8 shards

  // CSR build + weight prep (graph shared by both layers)
  k_init<<<NB_N, 256, 0, stream>>>(deg, fill, pooled, cnt);
  k_prep<<<(DIM * DIM + 255) / 256, 256, 0, stream>>>(W1, W2, wt1, wt2);
  k_count<<<NB_E, 256, 0, stream>>>(dst, deg);
  k_scan1<<<NB_SCAN, 256, 0, stream>>>(deg, offs, bsum);
  k_scan2<<<1, 256, 0, stream>>>(bsum, bpre);
  k_scan3<<<NB_SCAN, 256, 0, stream>>>(offs, bpre);
  k_selfloop<<<NB_N, 256, 0, stream>>>(offs, csr);
  k_scatter<<<NB_SC, 256, 0, stream>>>(src, dst, offs, fill, csr);

  // layer 1
  k_mm<0><<<NB_G, 256, 0, stream>>>(x, wt1, as1, ad1, h16, alpha_s, alpha_d, NN);
  k_sm_aggr<1><<<NB_W, 256, 0, stream>>>(offs, csr, alpha_s, alpha_d, h16, b1, nullptr, f116);

  // layer 2
  k_mm<1><<<NB_G, 256, 0, stream>>>(f116, wt2, as2, ad2, h16, alpha_s, alpha_d, NN);
  k_sm_aggr<0><<<NB_W, 256, 0, stream>>>(offs, csr, alpha_s, alpha_d, h16, b2, out_feats, nullptr);

  // pool
  k_pool_partial<<<PB, 256, 0, stream>>>(out_feats, batch, pooled, cnt);
  k_pool_norm<<<(NG * DIM + 255) / 256, 256, 0, stream>>>(pooled, cnt);
}

// Round 8
// 220.256 us; speedup vs baseline: 2.9273x; 1.0122x over previous
//
#include <hip/hip_runtime.h>

#define NN 50000
#define NE 800000
#define DIM 128
#define NG 64
#define ETOT (NE + NN)
#define NEG_SLOPE 0.2f
#define PB 200          // pooling blocks; chunk = 250 nodes
#define MAXLG 8         // local graph slots per block
#define NSH 8           // dst shards (== XCDs)
#define SHW ((NN + NSH - 1) / NSH)   // 6250 nodes per shard
#define NB_SCAN ((NN + 255) / 256)   // 196

typedef unsigned int uint32;
typedef unsigned short ushort;
typedef short bf16x8 __attribute__((ext_vector_type(8)));
typedef float f32x4 __attribute__((ext_vector_type(4)));

static __device__ __forceinline__ uint32 f2bf_pack(float lo, float hi) {
  uint32 a = __float_as_uint(lo), b = __float_as_uint(hi);
  a = (a + 0x7fffu + ((a >> 16) & 1u)) >> 16;          // RNE
  b = (b + 0x7fffu + ((b >> 16) & 1u)) >> 16;
  return a | (b << 16);
}
static __device__ __forceinline__ ushort f2bf1(float x) {
  uint32 a = __float_as_uint(x);
  a = (a + 0x7fffu + ((a >> 16) & 1u)) >> 16;
  return (ushort)a;
}
static __device__ __forceinline__ float bf_lo(uint32 u) { return __uint_as_float(u << 16); }
static __device__ __forceinline__ float bf_hi(uint32 u) { return __uint_as_float(u & 0xffff0000u); }

// ============================ init + weight prep (fused) ============================

__global__ __launch_bounds__(256) void k_init(const float* __restrict__ W1, const float* __restrict__ W2,
                                              ushort* __restrict__ wt1, ushort* __restrict__ wt2,
                                              int* deg, int* fill, float* pooled, float* cnt) {
  int i = blockIdx.x * 256 + threadIdx.x;
  if (i < NN) { deg[i] = 1; fill[i] = 1; }          // 1 = self-loop
  if (i < NG * DIM) pooled[i] = 0.f;
  if (i < NG) cnt[i] = 0.f;
  if (i < DIM * DIM) {                              // W^T bf16 rows (contiguous k) for MFMA B-frags
    int n = i >> 7, k = i & 127;
    wt1[i] = f2bf1(W1[k * DIM + n]);
    wt2[i] = f2bf1(W2[k * DIM + n]);
  }
}

__global__ __launch_bounds__(256) void k_count(const int* __restrict__ dst, int* __restrict__ deg) {
  int e = blockIdx.x * 256 + threadIdx.x;
  if (e < NE) atomicAdd(&deg[dst[e]], 1);
}

// ---- 3-phase multi-block inclusive scan: offs[i+1] = sum(deg[0..i]) ----

__global__ __launch_bounds__(256) void k_scan1(const int* __restrict__ deg, int* __restrict__ offs,
                                               int* __restrict__ bsum) {
  __shared__ int ws[4];
  const int i = blockIdx.x * 256 + threadIdx.x;
  const int lane = threadIdx.x & 63, wid = threadIdx.x >> 6;
  int x = (i < NN) ? deg[i] : 0;
#pragma unroll
  for (int off = 1; off < 64; off <<= 1) {
    int t = __shfl_up(x, off, 64);
    if (lane >= off) x += t;
  }
  if (lane == 63) ws[wid] = x;
  __syncthreads();
  int pre = 0;
#pragma unroll
  for (int j = 0; j < 3; ++j) if (j < wid) pre += ws[j];
  x += pre;
  if (i < NN) offs[i + 1] = x;
  if (threadIdx.x == 255) bsum[blockIdx.x] = x;
}

__global__ __launch_bounds__(256) void k_scan2(const int* __restrict__ bsum, int* __restrict__ bpre) {
  __shared__ int ws[4];
  const int b = threadIdx.x;
  const int lane = b & 63, wid = b >> 6;
  int v = (b < NB_SCAN) ? bsum[b] : 0;
  int x = v;
#pragma unroll
  for (int off = 1; off < 64; off <<= 1) {
    int t = __shfl_up(x, off, 64);
    if (lane >= off) x += t;
  }
  if (lane == 63) ws[wid] = x;
  __syncthreads();
  int pre = 0;
#pragma unroll
  for (int j = 0; j < 3; ++j) if (j < wid) pre += ws[j];
  x += pre;
  if (b < NB_SCAN) bpre[b] = x - v;     // exclusive prefix of block totals
}

__global__ __launch_bounds__(256) void k_scan3(int* __restrict__ offs, const int* __restrict__ bpre) {
  const int i = blockIdx.x * 256 + threadIdx.x;
  if (i < NN) offs[i + 1] += bpre[blockIdx.x];
  if (i == 0) offs[0] = 0;
}

__global__ __launch_bounds__(256) void k_selfloop(const int* __restrict__ offs, int* __restrict__ csr) {
  int i = blockIdx.x * 256 + threadIdx.x;
  if (i < NN) csr[offs[i]] = i;   // slot 0 of each segment = self-loop
}

// XCD-sharded scatter (round-5 notes): each csr line dirtied by one XCD only.
__global__ __launch_bounds__(256) void k_scatter(const int* __restrict__ src, const int* __restrict__ dst,
                                                 const int* __restrict__ offs, int* __restrict__ fill,
                                                 int* __restrict__ csr) {
  const int r = blockIdx.x & (NSH - 1);
  const int bi = blockIdx.x >> 3;
  const int nb = gridDim.x >> 3;
  const int lo = r * SHW, hi = min(lo + SHW, NN);
  for (int e = bi * 256 + threadIdx.x; e < NE; e += nb * 256) {
    int d = dst[e];
    if (d >= lo && d < hi) {
      int p = offs[d] + atomicAdd(&fill[d], 1);
      csr[p] = src[e];
    }
  }
}

// ============== MFMA GEMM: H16 = bf16(X @ W), alpha fused; A16=1 -> X is bf16-packed ==============

template <int A16>
__global__ __launch_bounds__(256) void k_mm(const void* __restrict__ Xv, const ushort* __restrict__ WT,
                                            const float* __restrict__ a_s, const float* __restrict__ a_d,
                                            uint32* __restrict__ H16,
                                            float* __restrict__ alpha_s, float* __restrict__ alpha_d, int n) {
  __shared__ __align__(16) ushort sWT[DIM * DIM];   // 32 KB
  __shared__ __align__(16) ushort sA[64 * DIM];     // 16 KB
  const int tid = threadIdx.x;
  const int row0 = blockIdx.x * 64;

  {  // stage W^T -> LDS (swizzled)
    const int nr = tid >> 1, h2 = tid & 1;
    const uint4* wp = (const uint4*)(WT + nr * DIM + h2 * 64);
#pragma unroll
    for (int i = 0; i < 8; ++i) {
      uint4 v = wp[i];
      int byte = nr * 256 + (((h2 * 128 + i * 16)) ^ ((nr & 7) << 4));
      *(uint4*)((char*)sWT + byte) = v;
    }
  }
  {  // stage A -> LDS (bf16, swizzled)
    const int r = tid >> 2, q = tid & 3;
    int rg = row0 + r; if (rg > n - 1) rg = n - 1;
    if (A16) {
      const uint4* xp = (const uint4*)((const uint32*)Xv + (size_t)rg * 64 + q * 16);
#pragma unroll
      for (int i = 0; i < 4; ++i) {
        uint4 pk = xp[i];
        int byte = r * 256 + ((q * 64 + i * 16) ^ ((r & 7) << 4));
        *(uint4*)((char*)sA + byte) = pk;
      }
    } else {
      const float4* xp = (const float4*)((const float*)Xv + (size_t)rg * DIM + q * 32);
#pragma unroll
      for (int i = 0; i < 4; ++i) {
        float4 v0 = xp[2 * i], v1 = xp[2 * i + 1];
        uint4 pk = make_uint4(f2bf_pack(v0.x, v0.y), f2bf_pack(v0.z, v0.w),
                              f2bf_pack(v1.x, v1.y), f2bf_pack(v1.z, v1.w));
        int byte = r * 256 + ((q * 64 + i * 16) ^ ((r & 7) << 4));
        *(uint4*)((char*)sA + byte) = pk;
      }
    }
  }
  __syncthreads();

  const int l = tid & 63, wv = tid >> 6;
  const int jr = l & 15, g = l >> 4;
  const int m0 = wv * 16;
  f32x4 acc[8];
#pragma unroll
  for (int nt = 0; nt < 8; ++nt) acc[nt] = (f32x4){0.f, 0.f, 0.f, 0.f};

  const int ra = m0 + jr;
  const int abase = ra * 256, aswz = (ra & 7) << 4;
  const int bswz = (jr & 7) << 4;
#pragma unroll
  for (int kk = 0; kk < 4; ++kk) {
    const int kb = kk * 64 + g * 16;
    bf16x8 af = *(const bf16x8*)((const char*)sA + abase + (kb ^ aswz));
#pragma unroll
    for (int nt = 0; nt < 8; ++nt) {
      bf16x8 bfg = *(const bf16x8*)((const char*)sWT + (nt * 16 + jr) * 256 + (kb ^ bswz));
      acc[nt] = __builtin_amdgcn_mfma_f32_16x16x32_bf16(af, bfg, acc[nt], 0, 0, 0);
    }
  }

  // fused alpha from f32 accumulators: row = m0 + g*4 + j, col = nt*16 + jr
  float asv[8], adv[8];
#pragma unroll
  for (int nt = 0; nt < 8; ++nt) { asv[nt] = a_s[nt * 16 + jr]; adv[nt] = a_d[nt * 16 + jr]; }
#pragma unroll
  for (int j = 0; j < 4; ++j) {
    float ps = 0.f, pd = 0.f;
#pragma unroll
    for (int nt = 0; nt < 8; ++nt) {
      ps = fmaf(acc[nt][j], asv[nt], ps);
      pd = fmaf(acc[nt][j], adv[nt], pd);
    }
#pragma unroll
    for (int off = 1; off < 16; off <<= 1) {
      ps += __shfl_xor(ps, off, 64);
      pd += __shfl_xor(pd, off, 64);
    }
    int r = row0 + m0 + g * 4 + j;
    if (jr == 0 && r < n) { alpha_s[r] = ps; alpha_d[r] = pd; }
  }

  // bf16 output bounce through this wave's own sA rows, then coalesced stores
  ushort* sOut = sA;
#pragma unroll
  for (int nt = 0; nt < 8; ++nt)
#pragma unroll
    for (int j = 0; j < 4; ++j)
      sOut[(m0 + g * 4 + j) * DIM + nt * 16 + jr] = f2bf1(acc[nt][j]);
#pragma unroll
  for (int i = 0; i < 4; ++i) {
    int r = row0 + m0 + (l >> 4) + i * 4;
    uint4 v = *(const uint4*)((const char*)sOut + m0 * 256 + l * 16 + i * 1024);
    if (r < n) *(uint4*)(H16 + (size_t)(row0 + m0) * 64 + l * 4 + i * 256) = v;
  }
}

// ============ fused edge-softmax + aggregation v2 ============
// 2 nodes per wave (32 lanes each), half feature row per block (half = blockIdx&1).
// Blocks round-robin over XCDs -> even XCDs only touch low 128B of h16 rows,
// odd XCDs the high 128B: per-XCD L2 footprint 6.4MB instead of 12.8MB, and
// each edge fetches one 128B line instead of two. Locality-only; any
// block->XCD mapping stays correct.

#define GATHER4(J)                                                          \
  { int s0 = __shfl(sv, g32 + (J), 64), s1 = __shfl(sv, g32 + (J) + 1, 64), \
        s2 = __shfl(sv, g32 + (J) + 2, 64), s3 = __shfl(sv, g32 + (J) + 3, 64); \
    float c0 = __shfl(ex, g32 + (J), 64), c1 = __shfl(ex, g32 + (J) + 1, 64), \
          c2 = __shfl(ex, g32 + (J) + 2, 64), c3 = __shfl(ex, g32 + (J) + 3, 64); \
    uint32 v0 = H16[(size_t)s0 * 64 + u0];                                  \
    uint32 v1 = H16[(size_t)s1 * 64 + u0];                                  \
    uint32 v2 = H16[(size_t)s2 * 64 + u0];                                  \
    uint32 v3 = H16[(size_t)s3 * 64 + u0];                                  \
    ax = fmaf(c0, bf_lo(v0), ax); ay = fmaf(c0, bf_hi(v0), ay);             \
    ax = fmaf(c1, bf_lo(v1), ax); ay = fmaf(c1, bf_hi(v1), ay);             \
    ax = fmaf(c2, bf_lo(v2), ax); ay = fmaf(c2, bf_hi(v2), ay);             \
    ax = fmaf(c3, bf_lo(v3), ax); ay = fmaf(c3, bf_hi(v3), ay); }

#define GATHER1(J)                                                          \
  { int s0 = __shfl(sv, g32 + (J), 64); float c0 = __shfl(ex, g32 + (J), 64); \
    uint32 v0 = H16[(size_t)s0 * 64 + u0];                                  \
    ax = fmaf(c0, bf_lo(v0), ax); ay = fmaf(c0, bf_hi(v0), ay); }

template <int STORE16>
__global__ __launch_bounds__(256) void k_sm_aggr2(const int* __restrict__ offs, const int* __restrict__ csr,
                                                  const float* __restrict__ alpha_s, const float* __restrict__ alpha_d,
                                                  const uint32* __restrict__ H16, const float* __restrict__ bias,
                                                  float* __restrict__ out, uint32* __restrict__ out16) {
  const int b = blockIdx.x;
  const int half = b & 1;                        // == XCD parity under round-robin dispatch
  const int l = threadIdx.x & 63;
  const int sl = l & 31, g = l >> 5, g32 = g * 32;
  const int pair = (b >> 1) * 4 + (threadIdx.x >> 6);   // 0..24999
  const int node = pair * 2 + g;
  const int bg = offs[node], eg = offs[node + 1];
  const int dg = eg - bg;
  const float ad = alpha_d[node];
  const int u0 = half * 32 + sl;                 // uint index within the row

  const int maxd = max(dg, __shfl_xor(dg, 32, 64));
  float ax = 0.f, ay = 0.f, ssum = 0.f;

  if (maxd <= 32) {                              // fast path (~99.9% of pairs)
    int sv = 0; float sc = -1e30f;
    if (sl < dg) {
      sv = csr[bg + sl];
      sc = alpha_s[sv] + ad;
      sc = sc > 0.f ? sc : NEG_SLOPE * sc;
    }
    float m = sc;
#pragma unroll
    for (int off = 1; off < 32; off <<= 1) m = fmaxf(m, __shfl_xor(m, off, 64));
    float ex = (sl < dg) ? __expf(sc - m) : 0.f;
    ssum = ex;
    int j = 0;
    for (; j + 3 < maxd; j += 4) GATHER4(j);
    for (; j < maxd; ++j) GATHER1(j);
  } else {                                       // chunked general path
    float m = -1e30f;
    for (int j = sl; j < dg; j += 32) {
      float sc = alpha_s[csr[bg + j]] + ad;
      sc = sc > 0.f ? sc : NEG_SLOPE * sc;
      m = fmaxf(m, sc);
    }
#pragma unroll
    for (int off = 1; off < 32; off <<= 1) m = fmaxf(m, __shfl_xor(m, off, 64));
    const int nch = (maxd + 31) >> 5;
    for (int c = 0; c < nch; ++c) {
      int j = c * 32 + sl;
      int sv = 0; float ex = 0.f;
      if (j < dg) {
        sv = csr[bg + j];
        float sc = alpha_s[sv] + ad;
        sc = sc > 0.f ? sc : NEG_SLOPE * sc;
        ex = __expf(sc - m);
      }
      ssum += ex;
      int cnt = min(32, maxd - c * 32);
      int jj = 0;
      for (; jj + 3 < cnt; jj += 4) GATHER4(jj);
      for (; jj < cnt; ++jj) GATHER1(jj);
    }
  }

#pragma unroll
  for (int off = 1; off < 32; off <<= 1) ssum += __shfl_xor(ssum, off, 64);
  const float inv = 1.f / (ssum + 1e-16f);
  const float2 bb = *(const float2*)(bias + 2 * u0);
  const float ox = ax * inv + bb.x, oy = ay * inv + bb.y;
  if (STORE16) {
    out16[(size_t)node * 64 + u0] = f2bf_pack(ox, oy);
  } else {
    *(float2*)(out + (size_t)node * DIM + 2 * u0) = make_float2(ox, oy);
  }
}

// ============================ global mean pool (hierarchical, batch sorted) ============================

__global__ __launch_bounds__(256) void k_pool_partial(const float* __restrict__ feats,
                                                      const int* __restrict__ batch,
                                                      float* __restrict__ pooled, float* __restrict__ cnt) {
  __shared__ float acc[4][MAXLG][DIM];
  __shared__ float lcnt[4][MAXLG];
  const int tid = threadIdx.x;
  const int wid = tid >> 6, l = tid & 63;
  for (int i = tid; i < 4 * MAXLG * DIM; i += 256) ((float*)acc)[i] = 0.f;
  if (tid < 4 * MAXLG) ((float*)lcnt)[tid] = 0.f;
  __syncthreads();

  const int chunk = (NN + PB - 1) / PB;
  const int beg = blockIdx.x * chunk;
  const int end = min(beg + chunk, NN);
  const int g0 = (beg < NN) ? batch[beg] : 0;

  for (int node = beg + wid; node < end; node += 4) {
    int lg = batch[node] - g0;
    float2 v = *(const float2*)(feats + (size_t)node * DIM + 2 * l);
    if (lg < MAXLG) {
      acc[wid][lg][2 * l] += v.x;
      acc[wid][lg][2 * l + 1] += v.y;
      if (l == 0) lcnt[wid][lg] += 1.f;
    } else {
      atomicAdd(&pooled[(g0 + lg) * DIM + 2 * l], v.x);
      atomicAdd(&pooled[(g0 + lg) * DIM + 2 * l + 1], v.y);
      if (l == 0) atomicAdd(&cnt[g0 + lg], 1.f);
    }
  }
  __syncthreads();

  for (int i = tid; i < MAXLG * DIM; i += 256) {
    int lg = i >> 7, d = i & (DIM - 1);
    float s = acc[0][lg][d] + acc[1][lg][d] + acc[2][lg][d] + acc[3][lg][d];
    if (s != 0.f) atomicAdd(&pooled[(g0 + lg) * DIM + d], s);
  }
  if (tid < MAXLG) {
    float s = lcnt[0][tid] + lcnt[1][tid] + lcnt[2][tid] + lcnt[3][tid];
    if (s != 0.f) atomicAdd(&cnt[g0 + tid], s);
  }
}

__global__ __launch_bounds__(256) void k_pool_norm(float* pooled, const float* __restrict__ cnt) {
  int i = blockIdx.x * 256 + threadIdx.x;
  if (i < NG * DIM) pooled[i] /= fmaxf(cnt[i >> 7], 1.f);
}

// ============================ launch ============================

static inline size_t pad256(size_t x) { return (x + 255) & ~(size_t)255; }

extern "C" void kernel_launch(void* const* d_in, const int* in_sizes, int n_in,
                              void* d_out, int out_size, void* d_ws, size_t ws_size,
                              hipStream_t stream) {
  const float* x   = (const float*)d_in[0];
  const int* ei    = (const int*)d_in[1];
  const int* batch = (const int*)d_in[2];
  const float* W1  = (const float*)d_in[3];
  const float* as1 = (const float*)d_in[4];
  const float* ad1 = (const float*)d_in[5];
  const float* b1  = (const float*)d_in[6];
  const float* W2  = (const float*)d_in[7];
  const float* as2 = (const float*)d_in[8];
  const float* ad2 = (const float*)d_in[9];
  const float* b2  = (const float*)d_in[10];

  float* out_feats = (float*)d_out;
  float* pooled    = out_feats + (size_t)NN * DIM;

  const int* src = ei;
  const int* dst = ei + NE;

  char* w = (char*)d_ws;
  uint32* h16 = (uint32*)w;   w += pad256((size_t)NN * 64 * 4);    // bf16-packed h (12.8 MB)
  uint32* f116 = (uint32*)w;  w += pad256((size_t)NN * 64 * 4);    // bf16-packed layer-1 out
  float* alpha_s = (float*)w; w += pad256((size_t)NN * 4);
  float* alpha_d = (float*)w; w += pad256((size_t)NN * 4);
  int* deg  = (int*)w;        w += pad256((size_t)NN * 4);
  int* offs = (int*)w;        w += pad256((size_t)(NN + 1) * 4);
  int* fill = (int*)w;        w += pad256((size_t)NN * 4);
  int* csr  = (int*)w;        w += pad256((size_t)ETOT * 4);
  float* cnt  = (float*)w;    w += pad256((size_t)NG * 4);
  int* bsum = (int*)w;        w += pad256((size_t)NB_SCAN * 4);
  int* bpre = (int*)w;        w += pad256((size_t)NB_SCAN * 4);
  ushort* wt1 = (ushort*)w;   w += pad256((size_t)DIM * DIM * 2);
  ushort* wt2 = (ushort*)w;   w += pad256((size_t)DIM * DIM * 2);

  const int NB_N = (NN + 255) / 256;
  const int NB_E = (NE + 255) / 256;
  const int NB_A = (NN / 2 / 4) * 2;            // 12500: 25000 pairs x 2 halves / 4 waves
  const int NB_G = (NN + 63) / 64;
  const int NB_SC = 1024;                       // sharded scatter: 128 blocks x 8 shards

  // CSR build + weight prep (graph shared by both layers)
  k_init<<<NB_N, 256, 0, stream>>>(W1, W2, wt1, wt2, deg, fill, pooled, cnt);
  k_count<<<NB_E, 256, 0, stream>>>(dst, deg);
  k_scan1<<<NB_SCAN, 256, 0, stream>>>(deg, offs, bsum);
  k_scan2<<<1, 256, 0, stream>>>(bsum, bpre);
  k_scan3<<<NB_SCAN, 256, 0, stream>>>(offs, bpre);
  k_selfloop<<<NB_N, 256, 0, stream>>>(offs, csr);
  k_scatter<<<NB_SC, 256, 0, stream>>>(src, dst, offs, fill, csr);

  // layer 1
  k_mm<0><<<NB_G, 256, 0, stream>>>(x, wt1, as1, ad1, h16, alpha_s, alpha_d, NN);
  k_sm_aggr2<1><<<NB_A, 256, 0, stream>>>(offs, csr, alpha_s, alpha_d, h16, b1, nullptr, f116);

  // layer 2
  k_mm<1><<<NB_G, 256, 0, stream>>>(f116, wt2, as2, ad2, h16, alpha_s, alpha_d, NN);
  k_sm_aggr2<0><<<NB_A, 256, 0, stream>>>(offs, csr, alpha_s, alpha_d, h16, b2, out_feats, nullptr);

  // pool
  k_pool_partial<<<PB, 256, 0, stream>>>(out_feats, batch, pooled, cnt);
  k_pool_norm<<<(NG * DIM + 255) / 256, 256, 0, stream>>>(pooled, cnt);
}